// Round 1
// baseline (5537.211 us; speedup 1.0000x reference)
//
#include <hip/hip_runtime.h>
#include <hip/hip_bf16.h>

#define N_NODES 50000
#define N_EDGES 800000
#define N_GRAPHS 64
#define FEAT 128
#define EMB 256
#define HID 512
#define VOCAB 512

// ---------------- scatter / degree kernels ----------------

__global__ void deg_kernel(const int* __restrict__ edge, float* __restrict__ deg) {
    int e = blockIdx.x * blockDim.x + threadIdx.x;
    if (e < N_EDGES) {
        int dst = edge[N_EDGES + e];
        atomicAdd(deg + dst, 1.0f);
    }
}

__global__ void ncnt_kernel(const int* __restrict__ batch, float* __restrict__ ncnt) {
    int i = blockIdx.x * blockDim.x + threadIdx.x;
    if (i < N_NODES) {
        atomicAdd(ncnt + batch[i], 1.0f);
    }
}

__global__ void rinv_kernel(const float* __restrict__ deg, float* __restrict__ rinv) {
    int i = blockIdx.x * blockDim.x + threadIdx.x;
    if (i < N_NODES) {
        rinv[i] = 1.0f / fmaxf(deg[i], 1.0f);
    }
}

// scatter x[src] (128 dims) into agg1[dst]; 32 threads per edge, float4 each
__global__ void scatter1_kernel(const int* __restrict__ edge, const float* __restrict__ x,
                                float* __restrict__ agg1) {
    long long tid = (long long)blockIdx.x * blockDim.x + threadIdx.x;
    if (tid >= (long long)N_EDGES * 32) return;
    int e = (int)(tid >> 5);
    int c = (int)(tid & 31);
    int src = edge[e];
    int dst = edge[N_EDGES + e];
    float4 v = *(const float4*)(x + (size_t)src * FEAT + c * 4);
    float* p = agg1 + (size_t)dst * FEAT + c * 4;
    atomicAdd(p + 0, v.x);
    atomicAdd(p + 1, v.y);
    atomicAdd(p + 2, v.z);
    atomicAdd(p + 3, v.w);
}

// scatter h1[src] (256 dims) into agg2[dst]; 64 threads per edge, float4 each
__global__ void scatter2_kernel(const int* __restrict__ edge, const float* __restrict__ h1,
                                float* __restrict__ agg2) {
    long long tid = (long long)blockIdx.x * blockDim.x + threadIdx.x;
    if (tid >= (long long)N_EDGES * 64) return;
    int e = (int)(tid >> 6);
    int c = (int)(tid & 63);
    int src = edge[e];
    int dst = edge[N_EDGES + e];
    float4 v = *(const float4*)(h1 + (size_t)src * EMB + c * 4);
    float* p = agg2 + (size_t)dst * EMB + c * 4;
    atomicAdd(p + 0, v.x);
    atomicAdd(p + 1, v.y);
    atomicAdd(p + 2, v.z);
    atomicAdd(p + 3, v.w);
}

// ---------------- fused RGCN layer GEMM ----------------
// out[r, :] = relu( A0[r,:]@W0 + (A1[r,:]*rinv[r])@W1 + bias )
// POOL: instead of storing, atomicAdd into psum[batch[r]*N + c]
template<int K1, int N, bool POOL>
__global__ __launch_bounds__(256) void rgcn_gemm(
    const float* __restrict__ A0, const float* __restrict__ A1,
    const float* __restrict__ rinv,
    const float* __restrict__ W0, const float* __restrict__ W1,
    const float* __restrict__ bias,
    float* __restrict__ out, float* __restrict__ psum,
    const int* __restrict__ batch, int M)
{
    constexpr int BM = 64, BN = 64, BK = 16;
    __shared__ float As[BK][BM + 4];
    __shared__ float Bs[BK][BN];

    const int bx = blockIdx.x;   // n tile
    const int by = blockIdx.y;   // m tile
    const int tid = threadIdx.x;
    const int tx = tid & 15, ty = tid >> 4;
    const int row0 = by * BM, col0 = bx * BN;

    const int arow = tid >> 2;          // 0..63
    const int kgrp = (tid & 3) * 4;     // 0,4,8,12
    const int brow = tid >> 4;          // 0..15
    const int bcol = (tid & 15) * 4;    // 0..60

    float acc[4][4] = {};
    constexpr int KT = (2 * K1) / BK;

    for (int kt = 0; kt < KT; ++kt) {
        const int kg = kt * BK;
        // --- load A tile (transposed into LDS) ---
        {
            int r = row0 + arow;
            float4 v = make_float4(0.f, 0.f, 0.f, 0.f);
            if (r < M) {
                if (kg < K1) {
                    v = *(const float4*)(A0 + (size_t)r * K1 + kg + kgrp);
                } else {
                    v = *(const float4*)(A1 + (size_t)r * K1 + (kg - K1) + kgrp);
                    float s = rinv[r];
                    v.x *= s; v.y *= s; v.z *= s; v.w *= s;
                }
            }
            As[kgrp + 0][arow] = v.x;
            As[kgrp + 1][arow] = v.y;
            As[kgrp + 2][arow] = v.z;
            As[kgrp + 3][arow] = v.w;
        }
        // --- load B tile ---
        {
            int k = kg + brow;
            const float* W = (k < K1) ? (W0 + (size_t)k * N) : (W1 + (size_t)(k - K1) * N);
            float4 v = *(const float4*)(W + col0 + bcol);
            *(float4*)&Bs[brow][bcol] = v;
        }
        __syncthreads();
        #pragma unroll
        for (int kk = 0; kk < BK; ++kk) {
            float a[4], b[4];
            #pragma unroll
            for (int i = 0; i < 4; ++i) a[i] = As[kk][ty * 4 + i];
            #pragma unroll
            for (int j = 0; j < 4; ++j) b[j] = Bs[kk][tx * 4 + j];
            #pragma unroll
            for (int i = 0; i < 4; ++i)
                #pragma unroll
                for (int j = 0; j < 4; ++j)
                    acc[i][j] += a[i] * b[j];
        }
        __syncthreads();
    }

    // --- epilogue ---
    #pragma unroll
    for (int i = 0; i < 4; ++i) {
        int r = row0 + ty * 4 + i;
        if (r >= M) continue;
        int c = col0 + tx * 4;
        if (!POOL) {
            float4 v;
            v.x = fmaxf(acc[i][0] + bias[c + 0], 0.f);
            v.y = fmaxf(acc[i][1] + bias[c + 1], 0.f);
            v.z = fmaxf(acc[i][2] + bias[c + 2], 0.f);
            v.w = fmaxf(acc[i][3] + bias[c + 3], 0.f);
            *(float4*)(out + (size_t)r * N + c) = v;
        } else {
            int g = batch[r];
            #pragma unroll
            for (int j = 0; j < 4; ++j) {
                float v = fmaxf(acc[i][j] + bias[c + j], 0.f);
                atomicAdd(psum + (size_t)g * N + c + j, v);
            }
        }
    }
}

// ---------------- head: pooled -> hidden, cell, log_softmax(logits) ----------------
__global__ __launch_bounds__(512) void head_kernel(
    const float* __restrict__ psum, const float* __restrict__ ncnt,
    const float* __restrict__ Wh, const float* __restrict__ bh,
    const float* __restrict__ Wc, const float* __restrict__ bc,
    const float* __restrict__ Wout, const float* __restrict__ bout,
    float* __restrict__ out)
{
    __shared__ float p[HID];
    __shared__ float hrow[HID];
    __shared__ float redm[8];
    __shared__ float reds[8];
    __shared__ float bm, bs;

    const int g = blockIdx.x;
    const int j = threadIdx.x;

    float inv = 1.0f / fmaxf(ncnt[g], 1.0f);
    p[j] = psum[(size_t)g * HID + j] * inv;
    __syncthreads();

    float h = bh[j], c = bc[j];
    for (int k = 0; k < HID; ++k) {
        float pk = p[k];
        h += pk * Wh[(size_t)k * HID + j];
        c += pk * Wc[(size_t)k * HID + j];
    }
    out[(size_t)N_GRAPHS * VOCAB + (size_t)g * HID + j] = h;       // hidden
    out[(size_t)2 * N_GRAPHS * VOCAB + (size_t)g * HID + j] = c;   // cell
    hrow[j] = h;
    __syncthreads();

    float l = bout[j];
    for (int k = 0; k < HID; ++k) l += hrow[k] * Wout[(size_t)k * VOCAB + j];

    // block-wide log_softmax over 512 threads
    const int lane = j & 63, wave = j >> 6;
    float m = l;
    #pragma unroll
    for (int o = 32; o > 0; o >>= 1) m = fmaxf(m, __shfl_down(m, o));
    if (lane == 0) redm[wave] = m;
    __syncthreads();
    if (j == 0) {
        float mm = redm[0];
        for (int w = 1; w < 8; ++w) mm = fmaxf(mm, redm[w]);
        bm = mm;
    }
    __syncthreads();
    m = bm;
    float e = __expf(l - m);
    float s = e;
    #pragma unroll
    for (int o = 32; o > 0; o >>= 1) s += __shfl_down(s, o);
    if (lane == 0) reds[wave] = s;
    __syncthreads();
    if (j == 0) {
        float ss = 0.f;
        for (int w = 0; w < 8; ++w) ss += reds[w];
        bs = ss;
    }
    __syncthreads();
    out[(size_t)g * VOCAB + j] = l - m - logf(bs);                  // logits
}

// ---------------- launch ----------------
extern "C" void kernel_launch(void* const* d_in, const int* in_sizes, int n_in,
                              void* d_out, int out_size, void* d_ws, size_t ws_size,
                              hipStream_t stream) {
    const float* x      = (const float*)d_in[1];
    const int*   edge   = (const int*)d_in[2];
    const int*   batch  = (const int*)d_in[3];
    const float* Wroot1 = (const float*)d_in[4];
    const float* Wrel1  = (const float*)d_in[5];
    const float* b1     = (const float*)d_in[6];
    const float* Wroot2 = (const float*)d_in[7];
    const float* Wrel2  = (const float*)d_in[8];
    const float* b2     = (const float*)d_in[9];
    const float* Wh     = (const float*)d_in[10];
    const float* bh     = (const float*)d_in[11];
    const float* Wc     = (const float*)d_in[12];
    const float* bc     = (const float*)d_in[13];
    const float* Wout   = (const float*)d_in[14];
    const float* bout   = (const float*)d_in[15];
    float* out = (float*)d_out;

    float* ws = (float*)d_ws;
    // workspace layout (floats)
    float* deg  = ws;                                    // 50000
    float* ncnt = ws + 50000;                            // 64
    float* psum = ws + 50064;                            // 32768
    float* agg1 = ws + 82832;                            // 6,400,000
    float* agg2 = agg1 + (size_t)N_NODES * FEAT;         // 12,800,000
    float* rinv = agg2 + (size_t)N_NODES * EMB;          // 50,000 (no zero needed)
    float* h1   = rinv + N_NODES;                        // 12,800,000 (no zero needed)

    const size_t zero_floats = 50000 + 64 + 32768 + (size_t)N_NODES * FEAT + (size_t)N_NODES * EMB;
    hipMemsetAsync(d_ws, 0, zero_floats * sizeof(float), stream);

    deg_kernel<<<(N_EDGES + 255) / 256, 256, 0, stream>>>(edge, deg);
    ncnt_kernel<<<(N_NODES + 255) / 256, 256, 0, stream>>>(batch, ncnt);
    scatter1_kernel<<<(int)(((long long)N_EDGES * 32) / 256), 256, 0, stream>>>(edge, x, agg1);
    rinv_kernel<<<(N_NODES + 255) / 256, 256, 0, stream>>>(deg, rinv);

    {   // layer 1: M=50000, K1=128, N=256  -> h1
        dim3 grid(EMB / 64, (N_NODES + 63) / 64);
        rgcn_gemm<FEAT, EMB, false><<<grid, 256, 0, stream>>>(
            x, agg1, rinv, Wroot1, Wrel1, b1, h1, nullptr, nullptr, N_NODES);
    }

    scatter2_kernel<<<(int)(((long long)N_EDGES * 64) / 256), 256, 0, stream>>>(edge, h1, agg2);

    {   // layer 2: M=50000, K1=256, N=512 -> pooled sums (h2 never stored)
        dim3 grid(HID / 64, (N_NODES + 63) / 64);
        rgcn_gemm<EMB, HID, true><<<grid, 256, 0, stream>>>(
            h1, agg2, rinv, Wroot2, Wrel2, b2, nullptr, psum, batch, N_NODES);
    }

    head_kernel<<<N_GRAPHS, 512, 0, stream>>>(psum, ncnt, Wh, bh, Wc, bc, Wout, bout, out);
}

// Round 2
// 1771.345 us; speedup vs baseline: 3.1260x; 3.1260x over previous
//
#include <hip/hip_runtime.h>
#include <hip/hip_bf16.h>

#define N_NODES 50000
#define N_EDGES 800000
#define N_GRAPHS 64
#define FEAT 128
#define EMB 256
#define HID 512
#define VOCAB 512

// ---------------- CSR build ----------------

__global__ void deg_kernel(const int* __restrict__ edge, int* __restrict__ deg) {
    int e = blockIdx.x * blockDim.x + threadIdx.x;
    if (e < N_EDGES) {
        atomicAdd(deg + edge[N_EDGES + e], 1);
    }
}

__global__ void ncnt_kernel(const int* __restrict__ batch, float* __restrict__ ncnt) {
    int i = blockIdx.x * blockDim.x + threadIdx.x;
    if (i < N_NODES) {
        atomicAdd(ncnt + batch[i], 1.0f);
    }
}

// single-block exclusive scan of deg -> offsets[0..N_NODES]
__global__ __launch_bounds__(1024) void scan_kernel(const int* __restrict__ deg,
                                                    int* __restrict__ offsets) {
    __shared__ int part[1024];
    const int T = 1024;
    const int CH = (N_NODES + T - 1) / T;   // 49
    int t = threadIdx.x;
    int b = t * CH, e = min(b + CH, N_NODES);
    int s = 0;
    for (int i = b; i < e; ++i) s += deg[i];
    part[t] = s;
    __syncthreads();
    for (int off = 1; off < T; off <<= 1) {
        int v = (t >= off) ? part[t - off] : 0;
        __syncthreads();
        part[t] += v;
        __syncthreads();
    }
    int run = (t == 0) ? 0 : part[t - 1];
    for (int i = b; i < e; ++i) { offsets[i] = run; run += deg[i]; }
    if (t == T - 1) offsets[N_NODES] = run;
}

__global__ void fill_kernel(const int* __restrict__ edge, const int* __restrict__ offsets,
                            int* __restrict__ cursor, int* __restrict__ srcbuf) {
    int e = blockIdx.x * blockDim.x + threadIdx.x;
    if (e < N_EDGES) {
        int src = edge[e];
        int dst = edge[N_EDGES + e];
        int pos = atomicAdd(cursor + dst, 1);
        srcbuf[offsets[dst] + pos] = src;
    }
}

__global__ void rinv_kernel(const int* __restrict__ offsets, float* __restrict__ rinv) {
    int i = blockIdx.x * blockDim.x + threadIdx.x;
    if (i < N_NODES) {
        int d = offsets[i + 1] - offsets[i];
        rinv[i] = 1.0f / (float)max(d, 1);
    }
}

// ---------------- CSR gathers (no atomics) ----------------
// one wave per node; lane handles float2 (FEAT=128) columns
__global__ __launch_bounds__(256) void gather1_kernel(
    const int* __restrict__ offsets, const int* __restrict__ srcbuf,
    const float* __restrict__ x, float* __restrict__ agg1)
{
    int node = blockIdx.x * 4 + (threadIdx.x >> 6);
    if (node >= N_NODES) return;
    int lane = threadIdx.x & 63;
    int beg = offsets[node], end = offsets[node + 1];
    float2 a0 = {0.f, 0.f}, a1 = {0.f, 0.f}, a2 = {0.f, 0.f}, a3 = {0.f, 0.f};
    int j = beg;
    for (; j + 4 <= end; j += 4) {
        int s0 = srcbuf[j], s1 = srcbuf[j + 1], s2 = srcbuf[j + 2], s3 = srcbuf[j + 3];
        float2 v0 = *(const float2*)(x + (size_t)s0 * FEAT + lane * 2);
        float2 v1 = *(const float2*)(x + (size_t)s1 * FEAT + lane * 2);
        float2 v2 = *(const float2*)(x + (size_t)s2 * FEAT + lane * 2);
        float2 v3 = *(const float2*)(x + (size_t)s3 * FEAT + lane * 2);
        a0.x += v0.x; a0.y += v0.y;
        a1.x += v1.x; a1.y += v1.y;
        a2.x += v2.x; a2.y += v2.y;
        a3.x += v3.x; a3.y += v3.y;
    }
    for (; j < end; ++j) {
        int s = srcbuf[j];
        float2 v = *(const float2*)(x + (size_t)s * FEAT + lane * 2);
        a0.x += v.x; a0.y += v.y;
    }
    float2 r;
    r.x = a0.x + a1.x + a2.x + a3.x;
    r.y = a0.y + a1.y + a2.y + a3.y;
    *(float2*)(agg1 + (size_t)node * FEAT + lane * 2) = r;
}

// one wave per node; lane handles float4 (EMB=256) columns
__global__ __launch_bounds__(256) void gather2_kernel(
    const int* __restrict__ offsets, const int* __restrict__ srcbuf,
    const float* __restrict__ h1, float* __restrict__ agg2)
{
    int node = blockIdx.x * 4 + (threadIdx.x >> 6);
    if (node >= N_NODES) return;
    int lane = threadIdx.x & 63;
    int beg = offsets[node], end = offsets[node + 1];
    float4 a0 = {0,0,0,0}, a1 = {0,0,0,0}, a2 = {0,0,0,0}, a3 = {0,0,0,0};
    int j = beg;
    for (; j + 4 <= end; j += 4) {
        int s0 = srcbuf[j], s1 = srcbuf[j + 1], s2 = srcbuf[j + 2], s3 = srcbuf[j + 3];
        float4 v0 = *(const float4*)(h1 + (size_t)s0 * EMB + lane * 4);
        float4 v1 = *(const float4*)(h1 + (size_t)s1 * EMB + lane * 4);
        float4 v2 = *(const float4*)(h1 + (size_t)s2 * EMB + lane * 4);
        float4 v3 = *(const float4*)(h1 + (size_t)s3 * EMB + lane * 4);
        a0.x += v0.x; a0.y += v0.y; a0.z += v0.z; a0.w += v0.w;
        a1.x += v1.x; a1.y += v1.y; a1.z += v1.z; a1.w += v1.w;
        a2.x += v2.x; a2.y += v2.y; a2.z += v2.z; a2.w += v2.w;
        a3.x += v3.x; a3.y += v3.y; a3.z += v3.z; a3.w += v3.w;
    }
    for (; j < end; ++j) {
        int s = srcbuf[j];
        float4 v = *(const float4*)(h1 + (size_t)s * EMB + lane * 4);
        a0.x += v.x; a0.y += v.y; a0.z += v.z; a0.w += v.w;
    }
    float4 r;
    r.x = a0.x + a1.x + a2.x + a3.x;
    r.y = a0.y + a1.y + a2.y + a3.y;
    r.z = a0.z + a1.z + a2.z + a3.z;
    r.w = a0.w + a1.w + a2.w + a3.w;
    *(float4*)(agg2 + (size_t)node * EMB + lane * 4) = r;
}

// ---------------- fused RGCN layer GEMM ----------------
// out[r, :] = relu( A0[r,:]@W0 + (A1[r,:]*rinv[r])@W1 + bias )
// POOL: instead of storing, atomicAdd into psum[batch[r]*N + c]
template<int K1, int N, bool POOL>
__global__ __launch_bounds__(256) void rgcn_gemm(
    const float* __restrict__ A0, const float* __restrict__ A1,
    const float* __restrict__ rinv,
    const float* __restrict__ W0, const float* __restrict__ W1,
    const float* __restrict__ bias,
    float* __restrict__ out, float* __restrict__ psum,
    const int* __restrict__ batch, int M)
{
    constexpr int BM = 64, BN = 64, BK = 16;
    __shared__ float As[BK][BM + 4];
    __shared__ float Bs[BK][BN];

    const int bx = blockIdx.x;   // n tile
    const int by = blockIdx.y;   // m tile
    const int tid = threadIdx.x;
    const int tx = tid & 15, ty = tid >> 4;
    const int row0 = by * BM, col0 = bx * BN;

    const int arow = tid >> 2;          // 0..63
    const int kgrp = (tid & 3) * 4;     // 0,4,8,12
    const int brow = tid >> 4;          // 0..15
    const int bcol = (tid & 15) * 4;    // 0..60

    float acc[4][4] = {};
    constexpr int KT = (2 * K1) / BK;

    for (int kt = 0; kt < KT; ++kt) {
        const int kg = kt * BK;
        {
            int r = row0 + arow;
            float4 v = make_float4(0.f, 0.f, 0.f, 0.f);
            if (r < M) {
                if (kg < K1) {
                    v = *(const float4*)(A0 + (size_t)r * K1 + kg + kgrp);
                } else {
                    v = *(const float4*)(A1 + (size_t)r * K1 + (kg - K1) + kgrp);
                    float s = rinv[r];
                    v.x *= s; v.y *= s; v.z *= s; v.w *= s;
                }
            }
            As[kgrp + 0][arow] = v.x;
            As[kgrp + 1][arow] = v.y;
            As[kgrp + 2][arow] = v.z;
            As[kgrp + 3][arow] = v.w;
        }
        {
            int k = kg + brow;
            const float* W = (k < K1) ? (W0 + (size_t)k * N) : (W1 + (size_t)(k - K1) * N);
            float4 v = *(const float4*)(W + col0 + bcol);
            *(float4*)&Bs[brow][bcol] = v;
        }
        __syncthreads();
        #pragma unroll
        for (int kk = 0; kk < BK; ++kk) {
            float a[4], b[4];
            #pragma unroll
            for (int i = 0; i < 4; ++i) a[i] = As[kk][ty * 4 + i];
            #pragma unroll
            for (int j = 0; j < 4; ++j) b[j] = Bs[kk][tx * 4 + j];
            #pragma unroll
            for (int i = 0; i < 4; ++i)
                #pragma unroll
                for (int j = 0; j < 4; ++j)
                    acc[i][j] += a[i] * b[j];
        }
        __syncthreads();
    }

    #pragma unroll
    for (int i = 0; i < 4; ++i) {
        int r = row0 + ty * 4 + i;
        if (r >= M) continue;
        int c = col0 + tx * 4;
        if (!POOL) {
            float4 v;
            v.x = fmaxf(acc[i][0] + bias[c + 0], 0.f);
            v.y = fmaxf(acc[i][1] + bias[c + 1], 0.f);
            v.z = fmaxf(acc[i][2] + bias[c + 2], 0.f);
            v.w = fmaxf(acc[i][3] + bias[c + 3], 0.f);
            *(float4*)(out + (size_t)r * N + c) = v;
        } else {
            int g = batch[r];
            #pragma unroll
            for (int j = 0; j < 4; ++j) {
                float v = fmaxf(acc[i][j] + bias[c + j], 0.f);
                atomicAdd(psum + (size_t)g * N + c + j, v);
            }
        }
    }
}

// ---------------- head ----------------
__global__ __launch_bounds__(512) void head_kernel(
    const float* __restrict__ psum, const float* __restrict__ ncnt,
    const float* __restrict__ Wh, const float* __restrict__ bh,
    const float* __restrict__ Wc, const float* __restrict__ bc,
    const float* __restrict__ Wout, const float* __restrict__ bout,
    float* __restrict__ out)
{
    __shared__ float p[HID];
    __shared__ float hrow[HID];
    __shared__ float redm[8];
    __shared__ float reds[8];
    __shared__ float bm, bs;

    const int g = blockIdx.x;
    const int j = threadIdx.x;

    float inv = 1.0f / fmaxf(ncnt[g], 1.0f);
    p[j] = psum[(size_t)g * HID + j] * inv;
    __syncthreads();

    float h = bh[j], c = bc[j];
    for (int k = 0; k < HID; ++k) {
        float pk = p[k];
        h += pk * Wh[(size_t)k * HID + j];
        c += pk * Wc[(size_t)k * HID + j];
    }
    out[(size_t)N_GRAPHS * VOCAB + (size_t)g * HID + j] = h;       // hidden
    out[(size_t)2 * N_GRAPHS * VOCAB + (size_t)g * HID + j] = c;   // cell
    hrow[j] = h;
    __syncthreads();

    float l = bout[j];
    for (int k = 0; k < HID; ++k) l += hrow[k] * Wout[(size_t)k * VOCAB + j];

    const int lane = j & 63, wave = j >> 6;
    float m = l;
    #pragma unroll
    for (int o = 32; o > 0; o >>= 1) m = fmaxf(m, __shfl_down(m, o));
    if (lane == 0) redm[wave] = m;
    __syncthreads();
    if (j == 0) {
        float mm = redm[0];
        for (int w = 1; w < 8; ++w) mm = fmaxf(mm, redm[w]);
        bm = mm;
    }
    __syncthreads();
    m = bm;
    float e = __expf(l - m);
    float s = e;
    #pragma unroll
    for (int o = 32; o > 0; o >>= 1) s += __shfl_down(s, o);
    if (lane == 0) reds[wave] = s;
    __syncthreads();
    if (j == 0) {
        float ss = 0.f;
        for (int w = 0; w < 8; ++w) ss += reds[w];
        bs = ss;
    }
    __syncthreads();
    out[(size_t)g * VOCAB + j] = l - m - logf(bs);                  // logits
}

// ---------------- launch ----------------
extern "C" void kernel_launch(void* const* d_in, const int* in_sizes, int n_in,
                              void* d_out, int out_size, void* d_ws, size_t ws_size,
                              hipStream_t stream) {
    const float* x      = (const float*)d_in[1];
    const int*   edge   = (const int*)d_in[2];
    const int*   batch  = (const int*)d_in[3];
    const float* Wroot1 = (const float*)d_in[4];
    const float* Wrel1  = (const float*)d_in[5];
    const float* b1     = (const float*)d_in[6];
    const float* Wroot2 = (const float*)d_in[7];
    const float* Wrel2  = (const float*)d_in[8];
    const float* b2     = (const float*)d_in[9];
    const float* Wh     = (const float*)d_in[10];
    const float* bh     = (const float*)d_in[11];
    const float* Wc     = (const float*)d_in[12];
    const float* bc     = (const float*)d_in[13];
    const float* Wout   = (const float*)d_in[14];
    const float* bout   = (const float*)d_in[15];
    float* out = (float*)d_out;

    // workspace layout (4-byte elements)
    int*   deg_i   = (int*)d_ws;                       // 50000   (zeroed)
    int*   cursor  = deg_i + N_NODES;                  // 50000   (zeroed)
    float* ncnt    = (float*)(cursor + N_NODES);       // 64      (zeroed)
    float* psum    = ncnt + N_GRAPHS;                  // 32768   (zeroed)
    int*   offsets = (int*)(psum + N_GRAPHS * HID);    // 50001
    int*   srcbuf  = offsets + (N_NODES + 1);          // 800000
    float* rinv    = (float*)(srcbuf + N_EDGES);       // 50000
    float* agg1    = rinv + N_NODES;                   // 6,400,000
    float* agg2    = agg1 + (size_t)N_NODES * FEAT;    // 12,800,000
    float* h1      = agg2 + (size_t)N_NODES * EMB;     // 12,800,000

    const size_t zero_bytes = (size_t)(N_NODES + N_NODES + N_GRAPHS + N_GRAPHS * HID) * 4;
    hipMemsetAsync(d_ws, 0, zero_bytes, stream);

    deg_kernel<<<(N_EDGES + 255) / 256, 256, 0, stream>>>(edge, deg_i);
    ncnt_kernel<<<(N_NODES + 255) / 256, 256, 0, stream>>>(batch, ncnt);
    scan_kernel<<<1, 1024, 0, stream>>>(deg_i, offsets);
    fill_kernel<<<(N_EDGES + 255) / 256, 256, 0, stream>>>(edge, offsets, cursor, srcbuf);
    rinv_kernel<<<(N_NODES + 255) / 256, 256, 0, stream>>>(offsets, rinv);

    gather1_kernel<<<(N_NODES + 3) / 4, 256, 0, stream>>>(offsets, srcbuf, x, agg1);

    {   // layer 1: M=50000, K1=128, N=256  -> h1
        dim3 grid(EMB / 64, (N_NODES + 63) / 64);
        rgcn_gemm<FEAT, EMB, false><<<grid, 256, 0, stream>>>(
            x, agg1, rinv, Wroot1, Wrel1, b1, h1, nullptr, nullptr, N_NODES);
    }

    gather2_kernel<<<(N_NODES + 3) / 4, 256, 0, stream>>>(offsets, srcbuf, h1, agg2);

    {   // layer 2: M=50000, K1=256, N=512 -> pooled sums (h2 never stored)
        dim3 grid(HID / 64, (N_NODES + 63) / 64);
        rgcn_gemm<EMB, HID, true><<<grid, 256, 0, stream>>>(
            h1, agg2, rinv, Wroot2, Wrel2, b2, nullptr, psum, batch, N_NODES);
    }

    head_kernel<<<N_GRAPHS, 512, 0, stream>>>(psum, ncnt, Wh, bh, Wc, bc, Wout, bout, out);
}

// Round 3
// 823.556 us; speedup vs baseline: 6.7235x; 2.1508x over previous
//
#include <hip/hip_runtime.h>
#include <hip/hip_bf16.h>

#define N_NODES 50000
#define N_EDGES 800000
#define N_GRAPHS 64
#define FEAT 128
#define EMB 256
#define HID 512
#define VOCAB 512

typedef __attribute__((ext_vector_type(8))) short short8;
typedef __attribute__((ext_vector_type(4))) float floatx4;
typedef unsigned short ushort_t;
typedef unsigned int uint32;

__device__ __forceinline__ ushort_t f2b(float f) {
    uint32 u = __builtin_bit_cast(uint32, f);
    u += 0x7fffu + ((u >> 16) & 1u);
    return (ushort_t)(u >> 16);
}
__device__ __forceinline__ float b2f(ushort_t h) {
    uint32 u = ((uint32)h) << 16;
    return __builtin_bit_cast(float, u);
}
__device__ __forceinline__ void async16(const void* g, void* l) {
    __builtin_amdgcn_global_load_lds(
        (const __attribute__((address_space(1))) void*)g,
        (__attribute__((address_space(3))) void*)l, 16, 0, 0);
}

// ---------------- CSR build ----------------

__global__ void deg_kernel(const int* __restrict__ edge, int* __restrict__ deg) {
    int e = blockIdx.x * blockDim.x + threadIdx.x;
    if (e < N_EDGES) atomicAdd(deg + edge[N_EDGES + e], 1);
}

__global__ void ncnt_kernel(const int* __restrict__ batch, float* __restrict__ ncnt) {
    int i = blockIdx.x * blockDim.x + threadIdx.x;
    if (i < N_NODES) atomicAdd(ncnt + batch[i], 1.0f);
}

__global__ __launch_bounds__(1024) void scan_kernel(const int* __restrict__ deg,
                                                    int* __restrict__ offsets) {
    __shared__ int part[1024];
    const int T = 1024;
    const int CH = (N_NODES + T - 1) / T;
    int t = threadIdx.x;
    int b = t * CH, e = min(b + CH, N_NODES);
    int s = 0;
    for (int i = b; i < e; ++i) s += deg[i];
    part[t] = s;
    __syncthreads();
    for (int off = 1; off < T; off <<= 1) {
        int v = (t >= off) ? part[t - off] : 0;
        __syncthreads();
        part[t] += v;
        __syncthreads();
    }
    int run = (t == 0) ? 0 : part[t - 1];
    for (int i = b; i < e; ++i) { offsets[i] = run; run += deg[i]; }
    if (t == T - 1) offsets[N_NODES] = run;
}

__global__ void fill_kernel(const int* __restrict__ edge, const int* __restrict__ offsets,
                            int* __restrict__ cursor, int* __restrict__ srcbuf) {
    int e = blockIdx.x * blockDim.x + threadIdx.x;
    if (e < N_EDGES) {
        int src = edge[e];
        int dst = edge[N_EDGES + e];
        int pos = atomicAdd(cursor + dst, 1);
        srcbuf[offsets[dst] + pos] = src;
    }
}

__global__ void rinv_kernel(const int* __restrict__ offsets, float* __restrict__ rinv) {
    int i = blockIdx.x * blockDim.x + threadIdx.x;
    if (i < N_NODES) {
        int d = offsets[i + 1] - offsets[i];
        rinv[i] = 1.0f / (float)max(d, 1);
    }
}

// ---------------- converts ----------------

__global__ void conv_x_kernel(const float* __restrict__ x, ushort_t* __restrict__ xb) {
    int tid = blockIdx.x * blockDim.x + threadIdx.x;   // N_NODES*32
    int row = tid >> 5, c = (tid & 31) * 4;
    float4 v = *(const float4*)(x + (size_t)row * FEAT + c);
    ushort4 o;
    o.x = f2b(v.x); o.y = f2b(v.y); o.z = f2b(v.z); o.w = f2b(v.w);
    *(ushort4*)(xb + (size_t)row * (2 * FEAT) + c) = o;
}

// Wt[n][k] = (k<K1 ? W0[k][n] : W1[k-K1][n]) as bf16; K = 2*K1 = 1<<kbits
__global__ void conv_wt_kernel(const float* __restrict__ W0, const float* __restrict__ W1,
                               int K1, int N, int kbits, ushort_t* __restrict__ Wt) {
    int tid = blockIdx.x * blockDim.x + threadIdx.x;
    int K = 1 << kbits;
    if (tid >= N * K) return;
    int n = tid >> kbits, k = tid & (K - 1);
    float v = (k < K1) ? W0[(size_t)k * N + n] : W1[(size_t)(k - K1) * N + n];
    Wt[tid] = f2b(v);
}

// ---------------- CSR gathers (bf16 in/out, fp32 accum) ----------------
// writes xb[node][128 + c] = bf16(sum * rinv); lane covers 2 cols (uint)
__global__ __launch_bounds__(256) void gather1_kernel(
    const int* __restrict__ offsets, const int* __restrict__ srcbuf,
    const float* __restrict__ rinv, ushort_t* __restrict__ xb)
{
    int node = blockIdx.x * 4 + (threadIdx.x >> 6);
    if (node >= N_NODES) return;
    int lane = threadIdx.x & 63;
    int beg = offsets[node], end = offsets[node + 1];
    float a0 = 0.f, a1 = 0.f, b0 = 0.f, b1 = 0.f;
    int j = beg;
    for (; j + 2 <= end; j += 2) {
        int s0 = srcbuf[j], s1 = srcbuf[j + 1];
        uint32 u0 = *(const uint32*)(xb + (size_t)s0 * 256 + lane * 2);
        uint32 u1 = *(const uint32*)(xb + (size_t)s1 * 256 + lane * 2);
        a0 += b2f((ushort_t)(u0 & 0xffff)); a1 += b2f((ushort_t)(u0 >> 16));
        b0 += b2f((ushort_t)(u1 & 0xffff)); b1 += b2f((ushort_t)(u1 >> 16));
    }
    for (; j < end; ++j) {
        uint32 u = *(const uint32*)(xb + (size_t)srcbuf[j] * 256 + lane * 2);
        a0 += b2f((ushort_t)(u & 0xffff)); a1 += b2f((ushort_t)(u >> 16));
    }
    float ri = rinv[node];
    uint32 o = (uint32)f2b((a0 + b0) * ri) | ((uint32)f2b((a1 + b1) * ri) << 16);
    *(uint32*)(xb + (size_t)node * 256 + 128 + lane * 2) = o;
}

// writes h1b[node][256 + c] = bf16(sum * rinv); lane covers 4 cols (uint2)
__global__ __launch_bounds__(256) void gather2_kernel(
    const int* __restrict__ offsets, const int* __restrict__ srcbuf,
    const float* __restrict__ rinv, ushort_t* __restrict__ h1b)
{
    int node = blockIdx.x * 4 + (threadIdx.x >> 6);
    if (node >= N_NODES) return;
    int lane = threadIdx.x & 63;
    int beg = offsets[node], end = offsets[node + 1];
    float s[4] = {0.f, 0.f, 0.f, 0.f};
    float t[4] = {0.f, 0.f, 0.f, 0.f};
    int j = beg;
    for (; j + 2 <= end; j += 2) {
        int s0 = srcbuf[j], s1 = srcbuf[j + 1];
        uint2 u0 = *(const uint2*)(h1b + (size_t)s0 * 512 + lane * 4);
        uint2 u1 = *(const uint2*)(h1b + (size_t)s1 * 512 + lane * 4);
        s[0] += b2f((ushort_t)(u0.x & 0xffff)); s[1] += b2f((ushort_t)(u0.x >> 16));
        s[2] += b2f((ushort_t)(u0.y & 0xffff)); s[3] += b2f((ushort_t)(u0.y >> 16));
        t[0] += b2f((ushort_t)(u1.x & 0xffff)); t[1] += b2f((ushort_t)(u1.x >> 16));
        t[2] += b2f((ushort_t)(u1.y & 0xffff)); t[3] += b2f((ushort_t)(u1.y >> 16));
    }
    for (; j < end; ++j) {
        uint2 u = *(const uint2*)(h1b + (size_t)srcbuf[j] * 512 + lane * 4);
        s[0] += b2f((ushort_t)(u.x & 0xffff)); s[1] += b2f((ushort_t)(u.x >> 16));
        s[2] += b2f((ushort_t)(u.y & 0xffff)); s[3] += b2f((ushort_t)(u.y >> 16));
    }
    float ri = rinv[node];
    uint2 o;
    o.x = (uint32)f2b((s[0] + t[0]) * ri) | ((uint32)f2b((s[1] + t[1]) * ri) << 16);
    o.y = (uint32)f2b((s[2] + t[2]) * ri) | ((uint32)f2b((s[3] + t[3]) * ri) << 16);
    *(uint2*)(h1b + (size_t)node * 512 + 256 + lane * 4) = o;
}

// ---------------- bf16 MFMA GEMM (128x128 tile, BK=32) ----------------
// C = relu(A[M x KTOT] @ Bt^T + bias); Bt is [N][KTOT] (pre-transposed weights).
// POOL=false: write bf16 to outb (row stride OUTSTR) at col offset col0.
// POOL=true : pool rows by batch[] into psum[g*HID + col] (batch sorted).
template<int KTOT, int OUTSTR, bool POOL>
__global__ __launch_bounds__(256) void mfma_gemm(
    const ushort_t* __restrict__ A, const ushort_t* __restrict__ Bt,
    const float* __restrict__ bias,
    ushort_t* __restrict__ outb, float* __restrict__ psum,
    const int* __restrict__ batch)
{
    __shared__ ushort_t As[4096];       // [128 rows][32 k]
    __shared__ ushort_t Bs[4096];       // [128 n][32 k]
    __shared__ float pool[16 * 128];

    const int tid = threadIdx.x;
    const int lane = tid & 63;
    const int wave = tid >> 6;
    const int quad = lane >> 4;
    const int l16 = lane & 15;
    const int m0w = (wave & 1) * 64;
    const int n0w = (wave >> 1) * 64;
    const int row0 = blockIdx.y * 128;
    const int col0 = blockIdx.x * 128;
    const int Mm1 = N_NODES - 1;

    floatx4 acc[4][4] = {};

    for (int kt = 0; kt < KTOT / 32; ++kt) {
        const int kb = kt * 32;
        #pragma unroll
        for (int c = 0; c < 2; ++c) {
            int idx = c * 256 + tid;
            int r = idx >> 2;
            int cb = (idx & 3) * 8;
            async16(A + (size_t)min(row0 + r, Mm1) * KTOT + kb + cb,
                    &As[(c * 4 + wave) * 512]);
        }
        #pragma unroll
        for (int c = 0; c < 2; ++c) {
            int idx = c * 256 + tid;
            int r = idx >> 2;
            int cb = (idx & 3) * 8;
            async16(Bt + (size_t)(col0 + r) * KTOT + kb + cb,
                    &Bs[(c * 4 + wave) * 512]);
        }
        __syncthreads();
        short8 a[4], b[4];
        #pragma unroll
        for (int t = 0; t < 4; ++t)
            a[t] = *(const short8*)&As[(m0w + t * 16 + l16) * 32 + quad * 8];
        #pragma unroll
        for (int t = 0; t < 4; ++t)
            b[t] = *(const short8*)&Bs[(n0w + t * 16 + l16) * 32 + quad * 8];
        #pragma unroll
        for (int i = 0; i < 4; ++i)
            #pragma unroll
            for (int j = 0; j < 4; ++j)
                acc[i][j] = __builtin_amdgcn_mfma_f32_16x16x32_bf16(a[i], b[j], acc[i][j], 0, 0, 0);
        __syncthreads();
    }

    float bias4[4];
    #pragma unroll
    for (int j = 0; j < 4; ++j) bias4[j] = bias[col0 + n0w + j * 16 + l16];

    if (!POOL) {
        #pragma unroll
        for (int i = 0; i < 4; ++i) {
            #pragma unroll
            for (int r = 0; r < 4; ++r) {
                int m = row0 + m0w + i * 16 + quad * 4 + r;
                if (m < N_NODES) {
                    #pragma unroll
                    for (int j = 0; j < 4; ++j) {
                        float v = fmaxf(acc[i][j][r] + bias4[j], 0.f);
                        outb[(size_t)m * OUTSTR + col0 + n0w + j * 16 + l16] = f2b(v);
                    }
                }
            }
        }
    } else {
        int gmin = batch[row0];
        int gmax = batch[min(row0 + 127, N_NODES - 1)];
        int span = gmax - gmin + 1;
        if (span <= 16) {
            for (int i = tid; i < span * 128; i += 256) pool[i] = 0.f;
            __syncthreads();
            #pragma unroll
            for (int i = 0; i < 4; ++i) {
                #pragma unroll
                for (int r = 0; r < 4; ++r) {
                    int m = row0 + m0w + i * 16 + quad * 4 + r;
                    if (m < N_NODES) {
                        int g = batch[m] - gmin;
                        #pragma unroll
                        for (int j = 0; j < 4; ++j) {
                            float v = fmaxf(acc[i][j][r] + bias4[j], 0.f);
                            atomicAdd(&pool[g * 128 + n0w + j * 16 + l16], v);
                        }
                    }
                }
            }
            __syncthreads();
            for (int i = tid; i < span * 128; i += 256) {
                float v = pool[i];
                if (v != 0.f)
                    atomicAdd(psum + (size_t)(gmin + (i >> 7)) * HID + col0 + (i & 127), v);
            }
        } else {
            #pragma unroll
            for (int i = 0; i < 4; ++i) {
                #pragma unroll
                for (int r = 0; r < 4; ++r) {
                    int m = row0 + m0w + i * 16 + quad * 4 + r;
                    if (m < N_NODES) {
                        int g = batch[m];
                        #pragma unroll
                        for (int j = 0; j < 4; ++j) {
                            float v = fmaxf(acc[i][j][r] + bias4[j], 0.f);
                            atomicAdd(psum + (size_t)g * HID + col0 + n0w + j * 16 + l16, v);
                        }
                    }
                }
            }
        }
    }
}

// ---------------- head ----------------
__global__ __launch_bounds__(512) void head_kernel(
    const float* __restrict__ psum, const float* __restrict__ ncnt,
    const float* __restrict__ Wh, const float* __restrict__ bh,
    const float* __restrict__ Wc, const float* __restrict__ bc,
    const float* __restrict__ Wout, const float* __restrict__ bout,
    float* __restrict__ out)
{
    __shared__ float p[HID];
    __shared__ float hrow[HID];
    __shared__ float redm[8];
    __shared__ float reds[8];
    __shared__ float bm, bs;

    const int g = blockIdx.x;
    const int j = threadIdx.x;

    float inv = 1.0f / fmaxf(ncnt[g], 1.0f);
    p[j] = psum[(size_t)g * HID + j] * inv;
    __syncthreads();

    float h = bh[j], c = bc[j];
    for (int k = 0; k < HID; ++k) {
        float pk = p[k];
        h += pk * Wh[(size_t)k * HID + j];
        c += pk * Wc[(size_t)k * HID + j];
    }
    out[(size_t)N_GRAPHS * VOCAB + (size_t)g * HID + j] = h;       // hidden
    out[(size_t)2 * N_GRAPHS * VOCAB + (size_t)g * HID + j] = c;   // cell
    hrow[j] = h;
    __syncthreads();

    float l = bout[j];
    for (int k = 0; k < HID; ++k) l += hrow[k] * Wout[(size_t)k * VOCAB + j];

    const int lane = j & 63, wave = j >> 6;
    float m = l;
    #pragma unroll
    for (int o = 32; o > 0; o >>= 1) m = fmaxf(m, __shfl_down(m, o));
    if (lane == 0) redm[wave] = m;
    __syncthreads();
    if (j == 0) {
        float mm = redm[0];
        for (int w = 1; w < 8; ++w) mm = fmaxf(mm, redm[w]);
        bm = mm;
    }
    __syncthreads();
    m = bm;
    float e = __expf(l - m);
    float s = e;
    #pragma unroll
    for (int o = 32; o > 0; o >>= 1) s += __shfl_down(s, o);
    if (lane == 0) reds[wave] = s;
    __syncthreads();
    if (j == 0) {
        float ss = 0.f;
        for (int w = 0; w < 8; ++w) ss += reds[w];
        bs = ss;
    }
    __syncthreads();
    out[(size_t)g * VOCAB + j] = l - m - logf(bs);                  // logits
}

// ---------------- launch ----------------
extern "C" void kernel_launch(void* const* d_in, const int* in_sizes, int n_in,
                              void* d_out, int out_size, void* d_ws, size_t ws_size,
                              hipStream_t stream) {
    const float* x      = (const float*)d_in[1];
    const int*   edge   = (const int*)d_in[2];
    const int*   batch  = (const int*)d_in[3];
    const float* Wroot1 = (const float*)d_in[4];
    const float* Wrel1  = (const float*)d_in[5];
    const float* b1     = (const float*)d_in[6];
    const float* Wroot2 = (const float*)d_in[7];
    const float* Wrel2  = (const float*)d_in[8];
    const float* b2     = (const float*)d_in[9];
    const float* Wh     = (const float*)d_in[10];
    const float* bh     = (const float*)d_in[11];
    const float* Wc     = (const float*)d_in[12];
    const float* bc     = (const float*)d_in[13];
    const float* Wout   = (const float*)d_in[14];
    const float* bout   = (const float*)d_in[15];
    float* out = (float*)d_out;

    // workspace layout
    int*      deg_i   = (int*)d_ws;                        // 50000 (zeroed)
    int*      cursor  = deg_i + N_NODES;                   // 50000 (zeroed)
    float*    ncnt    = (float*)(cursor + N_NODES);        // 64    (zeroed)
    float*    psum    = ncnt + N_GRAPHS;                   // 32768 (zeroed)
    int*      offsets = (int*)(psum + N_GRAPHS * HID);     // 50001
    int*      srcbuf  = offsets + (N_NODES + 1);           // 800000
    float*    rinv    = (float*)(srcbuf + N_EDGES);        // 50000 (+3 pad)
    ushort_t* xb      = (ushort_t*)(rinv + N_NODES + 3);   // 50000*256 bf16
    ushort_t* h1b     = xb + (size_t)N_NODES * 256;        // 50000*512 bf16
    ushort_t* w1t     = h1b + (size_t)N_NODES * 512;       // 256*256
    ushort_t* w2t     = w1t + 256 * 256;                   // 512*512

    const size_t zero_bytes = (size_t)(2 * N_NODES + N_GRAPHS + N_GRAPHS * HID) * 4;
    hipMemsetAsync(d_ws, 0, zero_bytes, stream);

    deg_kernel<<<(N_EDGES + 255) / 256, 256, 0, stream>>>(edge, deg_i);
    ncnt_kernel<<<(N_NODES + 255) / 256, 256, 0, stream>>>(batch, ncnt);
    scan_kernel<<<1, 1024, 0, stream>>>(deg_i, offsets);
    fill_kernel<<<(N_EDGES + 255) / 256, 256, 0, stream>>>(edge, offsets, cursor, srcbuf);
    rinv_kernel<<<(N_NODES + 255) / 256, 256, 0, stream>>>(offsets, rinv);

    conv_x_kernel<<<(N_NODES * 32) / 256, 256, 0, stream>>>(x, xb);
    conv_wt_kernel<<<(256 * 256) / 256, 256, 0, stream>>>(Wroot1, Wrel1, FEAT, EMB, 8, w1t);
    conv_wt_kernel<<<(512 * 512) / 256, 256, 0, stream>>>(Wroot2, Wrel2, EMB, HID, 9, w2t);

    gather1_kernel<<<(N_NODES + 3) / 4, 256, 0, stream>>>(offsets, srcbuf, rinv, xb);

    {   // layer 1: A=xb [50000 x 256] bf16, Wt=w1t [256 x 256] -> h1b cols 0..255
        dim3 grid(EMB / 128, (N_NODES + 127) / 128);
        mfma_gemm<256, 512, false><<<grid, 256, 0, stream>>>(
            xb, w1t, b1, h1b, nullptr, nullptr);
    }

    gather2_kernel<<<(N_NODES + 3) / 4, 256, 0, stream>>>(offsets, srcbuf, rinv, h1b);

    {   // layer 2: A=h1b [50000 x 512] bf16, Wt=w2t [512 x 512] -> pooled psum
        dim3 grid(HID / 128, (N_NODES + 127) / 128);
        mfma_gemm<512, 512, true><<<grid, 256, 0, stream>>>(
            h1b, w2t, b2, nullptr, psum, batch);
    }

    head_kernel<<<N_GRAPHS, 512, 0, stream>>>(psum, ncnt, Wh, bh, Wc, bc, Wout, bout, out);
}

// Round 4
// 671.629 us; speedup vs baseline: 8.2444x; 1.2262x over previous
//
#include <hip/hip_runtime.h>
#include <hip/hip_bf16.h>

#define N_NODES 50000
#define N_EDGES 800000
#define N_GRAPHS 64
#define FEAT 128
#define EMB 256
#define HID 512
#define VOCAB 512

typedef __attribute__((ext_vector_type(8))) short short8;
typedef __attribute__((ext_vector_type(4))) float floatx4;
typedef unsigned short ushort_t;
typedef unsigned int uint32;

__device__ __forceinline__ ushort_t f2b(float f) {
    uint32 u = __builtin_bit_cast(uint32, f);
    u += 0x7fffu + ((u >> 16) & 1u);
    return (ushort_t)(u >> 16);
}
__device__ __forceinline__ float b2f(ushort_t h) {
    uint32 u = ((uint32)h) << 16;
    return __builtin_bit_cast(float, u);
}
__device__ __forceinline__ void async16(const void* g, void* l) {
    __builtin_amdgcn_global_load_lds(
        (const __attribute__((address_space(1))) void*)g,
        (__attribute__((address_space(3))) void*)l, 16, 0, 0);
}

// ---------------- CSR build ----------------

__global__ void deg_kernel(const int* __restrict__ edge, int* __restrict__ deg) {
    int e = blockIdx.x * blockDim.x + threadIdx.x;
    if (e < N_EDGES) atomicAdd(deg + edge[N_EDGES + e], 1);
}

__global__ void ncnt_kernel(const int* __restrict__ batch, float* __restrict__ ncnt) {
    int i = blockIdx.x * blockDim.x + threadIdx.x;
    if (i < N_NODES) atomicAdd(ncnt + batch[i], 1.0f);
}

__global__ __launch_bounds__(1024) void scan_kernel(const int* __restrict__ deg,
                                                    int* __restrict__ offsets) {
    __shared__ int part[1024];
    const int T = 1024;
    const int CH = (N_NODES + T - 1) / T;
    int t = threadIdx.x;
    int b = t * CH, e = min(b + CH, N_NODES);
    int s = 0;
    for (int i = b; i < e; ++i) s += deg[i];
    part[t] = s;
    __syncthreads();
    for (int off = 1; off < T; off <<= 1) {
        int v = (t >= off) ? part[t - off] : 0;
        __syncthreads();
        part[t] += v;
        __syncthreads();
    }
    int run = (t == 0) ? 0 : part[t - 1];
    for (int i = b; i < e; ++i) { offsets[i] = run; run += deg[i]; }
    if (t == T - 1) offsets[N_NODES] = run;
}

__global__ void fill_kernel(const int* __restrict__ edge, const int* __restrict__ offsets,
                            int* __restrict__ cursor, int* __restrict__ srcbuf) {
    int e = blockIdx.x * blockDim.x + threadIdx.x;
    if (e < N_EDGES) {
        int src = edge[e];
        int dst = edge[N_EDGES + e];
        int pos = atomicAdd(cursor + dst, 1);
        srcbuf[offsets[dst] + pos] = src;
    }
}

__global__ void rinv_kernel(const int* __restrict__ offsets, float* __restrict__ rinv) {
    int i = blockIdx.x * blockDim.x + threadIdx.x;
    if (i < N_NODES) {
        int d = offsets[i + 1] - offsets[i];
        rinv[i] = 1.0f / (float)max(d, 1);
    }
}

// ---------------- converts ----------------

__global__ void conv_x_kernel(const float* __restrict__ x, ushort_t* __restrict__ xb) {
    int tid = blockIdx.x * blockDim.x + threadIdx.x;   // N_NODES*32
    int row = tid >> 5, c = (tid & 31) * 4;
    float4 v = *(const float4*)(x + (size_t)row * FEAT + c);
    ushort4 o;
    o.x = f2b(v.x); o.y = f2b(v.y); o.z = f2b(v.z); o.w = f2b(v.w);
    *(ushort4*)(xb + (size_t)row * (2 * FEAT) + c) = o;
}

// Wt[n][k] = (k<K1 ? W0[k][n] : W1[k-K1][n]) as bf16; K = 2*K1 = 1<<kbits
__global__ void conv_wt_kernel(const float* __restrict__ W0, const float* __restrict__ W1,
                               int K1, int N, int kbits, ushort_t* __restrict__ Wt) {
    int tid = blockIdx.x * blockDim.x + threadIdx.x;
    int K = 1 << kbits;
    if (tid >= N * K) return;
    int n = tid >> kbits, k = tid & (K - 1);
    float v = (k < K1) ? W0[(size_t)k * N + n] : W1[(size_t)(k - K1) * N + n];
    Wt[tid] = f2b(v);
}

// ---------------- CSR gathers (bf16 in/out, fp32 accum) ----------------
// writes xb[node][128 + c] = bf16(sum * rinv); lane covers 2 cols (uint)
__global__ __launch_bounds__(256) void gather1_kernel(
    const int* __restrict__ offsets, const int* __restrict__ srcbuf,
    const float* __restrict__ rinv, ushort_t* __restrict__ xb)
{
    int node = blockIdx.x * 4 + (threadIdx.x >> 6);
    if (node >= N_NODES) return;
    int lane = threadIdx.x & 63;
    int beg = offsets[node], end = offsets[node + 1];
    float a0 = 0.f, a1 = 0.f, b0 = 0.f, b1 = 0.f;
    float c0 = 0.f, c1 = 0.f, d0 = 0.f, d1 = 0.f;
    int j = beg;
    for (; j + 4 <= end; j += 4) {
        int s0 = srcbuf[j], s1 = srcbuf[j + 1], s2 = srcbuf[j + 2], s3 = srcbuf[j + 3];
        uint32 u0 = *(const uint32*)(xb + (size_t)s0 * 256 + lane * 2);
        uint32 u1 = *(const uint32*)(xb + (size_t)s1 * 256 + lane * 2);
        uint32 u2 = *(const uint32*)(xb + (size_t)s2 * 256 + lane * 2);
        uint32 u3 = *(const uint32*)(xb + (size_t)s3 * 256 + lane * 2);
        a0 += b2f((ushort_t)(u0 & 0xffff)); a1 += b2f((ushort_t)(u0 >> 16));
        b0 += b2f((ushort_t)(u1 & 0xffff)); b1 += b2f((ushort_t)(u1 >> 16));
        c0 += b2f((ushort_t)(u2 & 0xffff)); c1 += b2f((ushort_t)(u2 >> 16));
        d0 += b2f((ushort_t)(u3 & 0xffff)); d1 += b2f((ushort_t)(u3 >> 16));
    }
    for (; j < end; ++j) {
        uint32 u = *(const uint32*)(xb + (size_t)srcbuf[j] * 256 + lane * 2);
        a0 += b2f((ushort_t)(u & 0xffff)); a1 += b2f((ushort_t)(u >> 16));
    }
    float ri = rinv[node];
    uint32 o = (uint32)f2b((a0 + b0 + c0 + d0) * ri)
             | ((uint32)f2b((a1 + b1 + c1 + d1) * ri) << 16);
    *(uint32*)(xb + (size_t)node * 256 + 128 + lane * 2) = o;
}

// writes h1b[node][256 + c] = bf16(sum * rinv); lane covers 4 cols (uint2)
__global__ __launch_bounds__(256) void gather2_kernel(
    const int* __restrict__ offsets, const int* __restrict__ srcbuf,
    const float* __restrict__ rinv, ushort_t* __restrict__ h1b)
{
    int node = blockIdx.x * 4 + (threadIdx.x >> 6);
    if (node >= N_NODES) return;
    int lane = threadIdx.x & 63;
    int beg = offsets[node], end = offsets[node + 1];
    float s[4] = {0.f, 0.f, 0.f, 0.f};
    float t[4] = {0.f, 0.f, 0.f, 0.f};
    float u[4] = {0.f, 0.f, 0.f, 0.f};
    float v[4] = {0.f, 0.f, 0.f, 0.f};
    int j = beg;
    for (; j + 4 <= end; j += 4) {
        int s0 = srcbuf[j], s1 = srcbuf[j + 1], s2 = srcbuf[j + 2], s3 = srcbuf[j + 3];
        uint2 u0 = *(const uint2*)(h1b + (size_t)s0 * 512 + lane * 4);
        uint2 u1 = *(const uint2*)(h1b + (size_t)s1 * 512 + lane * 4);
        uint2 u2 = *(const uint2*)(h1b + (size_t)s2 * 512 + lane * 4);
        uint2 u3 = *(const uint2*)(h1b + (size_t)s3 * 512 + lane * 4);
        s[0] += b2f((ushort_t)(u0.x & 0xffff)); s[1] += b2f((ushort_t)(u0.x >> 16));
        s[2] += b2f((ushort_t)(u0.y & 0xffff)); s[3] += b2f((ushort_t)(u0.y >> 16));
        t[0] += b2f((ushort_t)(u1.x & 0xffff)); t[1] += b2f((ushort_t)(u1.x >> 16));
        t[2] += b2f((ushort_t)(u1.y & 0xffff)); t[3] += b2f((ushort_t)(u1.y >> 16));
        u[0] += b2f((ushort_t)(u2.x & 0xffff)); u[1] += b2f((ushort_t)(u2.x >> 16));
        u[2] += b2f((ushort_t)(u2.y & 0xffff)); u[3] += b2f((ushort_t)(u2.y >> 16));
        v[0] += b2f((ushort_t)(u3.x & 0xffff)); v[1] += b2f((ushort_t)(u3.x >> 16));
        v[2] += b2f((ushort_t)(u3.y & 0xffff)); v[3] += b2f((ushort_t)(u3.y >> 16));
    }
    for (; j < end; ++j) {
        uint2 uu = *(const uint2*)(h1b + (size_t)srcbuf[j] * 512 + lane * 4);
        s[0] += b2f((ushort_t)(uu.x & 0xffff)); s[1] += b2f((ushort_t)(uu.x >> 16));
        s[2] += b2f((ushort_t)(uu.y & 0xffff)); s[3] += b2f((ushort_t)(uu.y >> 16));
    }
    float ri = rinv[node];
    uint2 o;
    o.x = (uint32)f2b((s[0] + t[0] + u[0] + v[0]) * ri)
        | ((uint32)f2b((s[1] + t[1] + u[1] + v[1]) * ri) << 16);
    o.y = (uint32)f2b((s[2] + t[2] + u[2] + v[2]) * ri)
        | ((uint32)f2b((s[3] + t[3] + u[3] + v[3]) * ri) << 16);
    *(uint2*)(h1b + (size_t)node * 512 + 256 + lane * 4) = o;
}

// ---------------- bf16 MFMA GEMM (128x128 tile, BK=32, XOR-swizzled LDS) ----------------
// C = relu(A[M x KTOT] @ Bt^T + bias); Bt is [N][KTOT] (pre-transposed weights).
// POOL=false: write bf16 to outb (row stride OUTSTR) at col offset col0.
// POOL=true : pool rows by batch[] into psum[g*HID + col] (batch sorted).
template<int KTOT, int OUTSTR, bool POOL>
__global__ __launch_bounds__(256) void mfma_gemm(
    const ushort_t* __restrict__ A, const ushort_t* __restrict__ Bt,
    const float* __restrict__ bias,
    ushort_t* __restrict__ outb, float* __restrict__ psum,
    const int* __restrict__ batch)
{
    __shared__ ushort_t As[4096];       // [128 rows][32 k], chunk-swizzled
    __shared__ ushort_t Bs[4096];       // [128 n][32 k], chunk-swizzled
    __shared__ float pool2[8 * 128];    // POOL reduction scratch (4 KB)

    const int tid = threadIdx.x;
    const int lane = tid & 63;
    const int wave = tid >> 6;
    const int quad = lane >> 4;
    const int l16 = lane & 15;
    const int m0w = (wave & 1) * 64;
    const int n0w = (wave >> 1) * 64;
    const int row0 = blockIdx.y * 128;
    const int col0 = blockIdx.x * 128;
    const int Mm1 = N_NODES - 1;

    // swizzle: LDS slot (r, q) holds global chunk q ^ ((r>>1)&3) (16B chunks)
    const int sw = (l16 >> 1) & 3;
    const int co = (quad ^ sw) * 8;     // element offset of chunk `quad` of row l16-class

    // staging source addresses (per-lane): slot idx = c*256 + tid
    int st_r[2], st_cb[2];
    #pragma unroll
    for (int c = 0; c < 2; ++c) {
        int idx = c * 256 + tid;
        int r = idx >> 2;
        int q = idx & 3;
        st_r[c] = r;
        st_cb[c] = (q ^ ((r >> 1) & 3)) * 8;
    }

    floatx4 acc[4][4] = {};

    for (int kt = 0; kt < KTOT / 32; ++kt) {
        const int kb = kt * 32;
        #pragma unroll
        for (int c = 0; c < 2; ++c) {
            async16(A + (size_t)min(row0 + st_r[c], Mm1) * KTOT + kb + st_cb[c],
                    &As[(c * 4 + wave) * 512]);
        }
        #pragma unroll
        for (int c = 0; c < 2; ++c) {
            async16(Bt + (size_t)(col0 + st_r[c]) * KTOT + kb + st_cb[c],
                    &Bs[(c * 4 + wave) * 512]);
        }
        __syncthreads();
        short8 a[4], b[4];
        #pragma unroll
        for (int t = 0; t < 4; ++t)
            a[t] = *(const short8*)&As[(m0w + t * 16 + l16) * 32 + co];
        #pragma unroll
        for (int t = 0; t < 4; ++t)
            b[t] = *(const short8*)&Bs[(n0w + t * 16 + l16) * 32 + co];
        #pragma unroll
        for (int i = 0; i < 4; ++i)
            #pragma unroll
            for (int j = 0; j < 4; ++j)
                acc[i][j] = __builtin_amdgcn_mfma_f32_16x16x32_bf16(a[i], b[j], acc[i][j], 0, 0, 0);
        __syncthreads();
    }

    float bias4[4];
    #pragma unroll
    for (int j = 0; j < 4; ++j) bias4[j] = bias[col0 + n0w + j * 16 + l16];

    if (!POOL) {
        #pragma unroll
        for (int i = 0; i < 4; ++i) {
            #pragma unroll
            for (int r = 0; r < 4; ++r) {
                int m = row0 + m0w + i * 16 + quad * 4 + r;
                if (m < N_NODES) {
                    #pragma unroll
                    for (int j = 0; j < 4; ++j) {
                        float v = fmaxf(acc[i][j][r] + bias4[j], 0.f);
                        outb[(size_t)m * OUTSTR + col0 + n0w + j * 16 + l16] = f2b(v);
                    }
                }
            }
        }
    } else {
        int gmin = batch[row0];
        int gmax = batch[min(row0 + 127, N_NODES - 1)];
        int span = gmax - gmin + 1;
        if (span == 1) {
            // single-graph tile: register-reduce 16 rows, non-atomic pool2 write
            float s[4] = {0.f, 0.f, 0.f, 0.f};
            #pragma unroll
            for (int i = 0; i < 4; ++i) {
                #pragma unroll
                for (int r = 0; r < 4; ++r) {
                    int m = row0 + m0w + i * 16 + quad * 4 + r;
                    if (m < N_NODES) {
                        #pragma unroll
                        for (int j = 0; j < 4; ++j)
                            s[j] += fmaxf(acc[i][j][r] + bias4[j], 0.f);
                    }
                }
            }
            int slot = (wave & 1) * 4 + quad;
            #pragma unroll
            for (int j = 0; j < 4; ++j)
                pool2[slot * 128 + n0w + j * 16 + l16] = s[j];
            __syncthreads();
            if (tid < 128) {
                float v = 0.f;
                #pragma unroll
                for (int k = 0; k < 8; ++k) v += pool2[k * 128 + tid];
                atomicAdd(psum + (size_t)gmin * HID + col0 + tid, v);
            }
        } else if (span <= 8) {
            // boundary tile: run-compressed LDS atomics (<= span flushes/thread)
            for (int i = tid; i < span * 128; i += 256) pool2[i] = 0.f;
            __syncthreads();
            float s[4] = {0.f, 0.f, 0.f, 0.f};
            int cg = -1;
            #pragma unroll
            for (int i = 0; i < 4; ++i) {
                #pragma unroll
                for (int r = 0; r < 4; ++r) {
                    int m = row0 + m0w + i * 16 + quad * 4 + r;
                    if (m < N_NODES) {
                        int g = batch[m] - gmin;
                        if (g != cg) {
                            if (cg >= 0) {
                                #pragma unroll
                                for (int j = 0; j < 4; ++j)
                                    atomicAdd(&pool2[cg * 128 + n0w + j * 16 + l16], s[j]);
                            }
                            cg = g;
                            s[0] = s[1] = s[2] = s[3] = 0.f;
                        }
                        #pragma unroll
                        for (int j = 0; j < 4; ++j)
                            s[j] += fmaxf(acc[i][j][r] + bias4[j], 0.f);
                    }
                }
            }
            if (cg >= 0) {
                #pragma unroll
                for (int j = 0; j < 4; ++j)
                    atomicAdd(&pool2[cg * 128 + n0w + j * 16 + l16], s[j]);
            }
            __syncthreads();
            for (int i = tid; i < span * 128; i += 256) {
                float v = pool2[i];
                if (v != 0.f)
                    atomicAdd(psum + (size_t)(gmin + (i >> 7)) * HID + col0 + (i & 127), v);
            }
        } else {
            // pathological: direct global atomics
            #pragma unroll
            for (int i = 0; i < 4; ++i) {
                #pragma unroll
                for (int r = 0; r < 4; ++r) {
                    int m = row0 + m0w + i * 16 + quad * 4 + r;
                    if (m < N_NODES) {
                        int g = batch[m];
                        #pragma unroll
                        for (int j = 0; j < 4; ++j) {
                            float v = fmaxf(acc[i][j][r] + bias4[j], 0.f);
                            atomicAdd(psum + (size_t)g * HID + col0 + n0w + j * 16 + l16, v);
                        }
                    }
                }
            }
        }
    }
}

// ---------------- head ----------------
__global__ __launch_bounds__(512) void head_kernel(
    const float* __restrict__ psum, const float* __restrict__ ncnt,
    const float* __restrict__ Wh, const float* __restrict__ bh,
    const float* __restrict__ Wc, const float* __restrict__ bc,
    const float* __restrict__ Wout, const float* __restrict__ bout,
    float* __restrict__ out)
{
    __shared__ float p[HID];
    __shared__ float hrow[HID];
    __shared__ float redm[8];
    __shared__ float reds[8];
    __shared__ float bm, bs;

    const int g = blockIdx.x;
    const int j = threadIdx.x;

    float inv = 1.0f / fmaxf(ncnt[g], 1.0f);
    p[j] = psum[(size_t)g * HID + j] * inv;
    __syncthreads();

    float h = bh[j], c = bc[j];
    for (int k = 0; k < HID; ++k) {
        float pk = p[k];
        h += pk * Wh[(size_t)k * HID + j];
        c += pk * Wc[(size_t)k * HID + j];
    }
    out[(size_t)N_GRAPHS * VOCAB + (size_t)g * HID + j] = h;       // hidden
    out[(size_t)2 * N_GRAPHS * VOCAB + (size_t)g * HID + j] = c;   // cell
    hrow[j] = h;
    __syncthreads();

    float l = bout[j];
    for (int k = 0; k < HID; ++k) l += hrow[k] * Wout[(size_t)k * VOCAB + j];

    const int lane = j & 63, wave = j >> 6;
    float m = l;
    #pragma unroll
    for (int o = 32; o > 0; o >>= 1) m = fmaxf(m, __shfl_down(m, o));
    if (lane == 0) redm[wave] = m;
    __syncthreads();
    if (j == 0) {
        float mm = redm[0];
        for (int w = 1; w < 8; ++w) mm = fmaxf(mm, redm[w]);
        bm = mm;
    }
    __syncthreads();
    m = bm;
    float e = __expf(l - m);
    float s = e;
    #pragma unroll
    for (int o = 32; o > 0; o >>= 1) s += __shfl_down(s, o);
    if (lane == 0) reds[wave] = s;
    __syncthreads();
    if (j == 0) {
        float ss = 0.f;
        for (int w = 0; w < 8; ++w) ss += reds[w];
        bs = ss;
    }
    __syncthreads();
    out[(size_t)g * VOCAB + j] = l - m - logf(bs);                  // logits
}

// ---------------- launch ----------------
extern "C" void kernel_launch(void* const* d_in, const int* in_sizes, int n_in,
                              void* d_out, int out_size, void* d_ws, size_t ws_size,
                              hipStream_t stream) {
    const float* x      = (const float*)d_in[1];
    const int*   edge   = (const int*)d_in[2];
    const int*   batch  = (const int*)d_in[3];
    const float* Wroot1 = (const float*)d_in[4];
    const float* Wrel1  = (const float*)d_in[5];
    const float* b1     = (const float*)d_in[6];
    const float* Wroot2 = (const float*)d_in[7];
    const float* Wrel2  = (const float*)d_in[8];
    const float* b2     = (const float*)d_in[9];
    const float* Wh     = (const float*)d_in[10];
    const float* bh     = (const float*)d_in[11];
    const float* Wc     = (const float*)d_in[12];
    const float* bc     = (const float*)d_in[13];
    const float* Wout   = (const float*)d_in[14];
    const float* bout   = (const float*)d_in[15];
    float* out = (float*)d_out;

    // workspace layout
    int*      deg_i   = (int*)d_ws;                        // 50000 (zeroed)
    int*      cursor  = deg_i + N_NODES;                   // 50000 (zeroed)
    float*    ncnt    = (float*)(cursor + N_NODES);        // 64    (zeroed)
    float*    psum    = ncnt + N_GRAPHS;                   // 32768 (zeroed)
    int*      offsets = (int*)(psum + N_GRAPHS * HID);     // 50001
    int*      srcbuf  = offsets + (N_NODES + 1);           // 800000
    float*    rinv    = (float*)(srcbuf + N_EDGES);        // 50000 (+3 pad)
    ushort_t* xb      = (ushort_t*)(rinv + N_NODES + 3);   // 50000*256 bf16
    ushort_t* h1b     = xb + (size_t)N_NODES * 256;        // 50000*512 bf16
    ushort_t* w1t     = h1b + (size_t)N_NODES * 512;       // 256*256
    ushort_t* w2t     = w1t + 256 * 256;                   // 512*512

    const size_t zero_bytes = (size_t)(2 * N_NODES + N_GRAPHS + N_GRAPHS * HID) * 4;
    hipMemsetAsync(d_ws, 0, zero_bytes, stream);

    deg_kernel<<<(N_EDGES + 255) / 256, 256, 0, stream>>>(edge, deg_i);
    ncnt_kernel<<<(N_NODES + 255) / 256, 256, 0, stream>>>(batch, ncnt);
    scan_kernel<<<1, 1024, 0, stream>>>(deg_i, offsets);
    fill_kernel<<<(N_EDGES + 255) / 256, 256, 0, stream>>>(edge, offsets, cursor, srcbuf);
    rinv_kernel<<<(N_NODES + 255) / 256, 256, 0, stream>>>(offsets, rinv);

    conv_x_kernel<<<(N_NODES * 32) / 256, 256, 0, stream>>>(x, xb);
    conv_wt_kernel<<<(256 * 256) / 256, 256, 0, stream>>>(Wroot1, Wrel1, FEAT, EMB, 8, w1t);
    conv_wt_kernel<<<(512 * 512) / 256, 256, 0, stream>>>(Wroot2, Wrel2, EMB, HID, 9, w2t);

    gather1_kernel<<<(N_NODES + 3) / 4, 256, 0, stream>>>(offsets, srcbuf, rinv, xb);

    {   // layer 1: A=xb [50000 x 256] bf16, Wt=w1t [256 x 256] -> h1b cols 0..255
        dim3 grid(EMB / 128, (N_NODES + 127) / 128);
        mfma_gemm<256, 512, false><<<grid, 256, 0, stream>>>(
            xb, w1t, b1, h1b, nullptr, nullptr);
    }

    gather2_kernel<<<(N_NODES + 3) / 4, 256, 0, stream>>>(offsets, srcbuf, rinv, h1b);

    {   // layer 2: A=h1b [50000 x 512] bf16, Wt=w2t [512 x 512] -> pooled psum
        dim3 grid(HID / 128, (N_NODES + 127) / 128);
        mfma_gemm<512, 512, true><<<grid, 256, 0, stream>>>(
            h1b, w2t, b2, nullptr, psum, batch);
    }

    head_kernel<<<N_GRAPHS, 512, 0, stream>>>(psum, ncnt, Wh, bh, Wc, bc, Wout, bout, out);
}

// Round 5
// 514.720 us; speedup vs baseline: 10.7577x; 1.3048x over previous
//
#include <hip/hip_runtime.h>
#include <hip/hip_bf16.h>

#define N_NODES 50000
#define N_EDGES 800000
#define N_GRAPHS 64
#define FEAT 128
#define EMB 256
#define HID 512
#define VOCAB 512

typedef __attribute__((ext_vector_type(8))) short short8;
typedef __attribute__((ext_vector_type(4))) float floatx4;
typedef unsigned short ushort_t;
typedef unsigned int uint32;

__device__ __forceinline__ ushort_t f2b(float f) {
    uint32 u = __builtin_bit_cast(uint32, f);
    u += 0x7fffu + ((u >> 16) & 1u);
    return (ushort_t)(u >> 16);
}
__device__ __forceinline__ float b2f(ushort_t h) {
    uint32 u = ((uint32)h) << 16;
    return __builtin_bit_cast(float, u);
}
__device__ __forceinline__ void async16(const void* g, void* l) {
    __builtin_amdgcn_global_load_lds(
        (const __attribute__((address_space(1))) void*)g,
        (__attribute__((address_space(3))) void*)l, 16, 0, 0);
}

// ---------------- CSR build ----------------

__global__ void deg_kernel(const int* __restrict__ edge, int* __restrict__ deg) {
    int e = blockIdx.x * blockDim.x + threadIdx.x;
    if (e < N_EDGES) atomicAdd(deg + edge[N_EDGES + e], 1);
}

// batch is sorted: ncnt[g] = lower_bound(g+1) - lower_bound(g). one block, 64 threads.
__global__ void ncnt_bs_kernel(const int* __restrict__ batch, float* __restrict__ ncnt) {
    int g = threadIdx.x;
    if (g >= N_GRAPHS) return;
    int lo = 0, hi = N_NODES;
    while (lo < hi) { int mid = (lo + hi) >> 1; if (batch[mid] < g) lo = mid + 1; else hi = mid; }
    int lo2 = lo, hi2 = N_NODES;
    while (lo2 < hi2) { int mid = (lo2 + hi2) >> 1; if (batch[mid] < g + 1) lo2 = mid + 1; else hi2 = mid; }
    ncnt[g] = (float)(lo2 - lo);
}

__global__ __launch_bounds__(1024) void scan_kernel(const int* __restrict__ deg,
                                                    int* __restrict__ offsets) {
    __shared__ int part[1024];
    const int T = 1024;
    const int CH = (N_NODES + T - 1) / T;
    int t = threadIdx.x;
    int b = t * CH, e = min(b + CH, N_NODES);
    int s = 0;
    for (int i = b; i < e; ++i) s += deg[i];
    part[t] = s;
    __syncthreads();
    for (int off = 1; off < T; off <<= 1) {
        int v = (t >= off) ? part[t - off] : 0;
        __syncthreads();
        part[t] += v;
        __syncthreads();
    }
    int run = (t == 0) ? 0 : part[t - 1];
    for (int i = b; i < e; ++i) { offsets[i] = run; run += deg[i]; }
    if (t == T - 1) offsets[N_NODES] = run;
}

__global__ void fill_kernel(const int* __restrict__ edge, const int* __restrict__ offsets,
                            int* __restrict__ cursor, int* __restrict__ srcbuf) {
    int e = blockIdx.x * blockDim.x + threadIdx.x;
    if (e < N_EDGES) {
        int src = edge[e];
        int dst = edge[N_EDGES + e];
        int pos = atomicAdd(cursor + dst, 1);
        srcbuf[offsets[dst] + pos] = src;
    }
}

__global__ void rinv_kernel(const int* __restrict__ offsets, float* __restrict__ rinv) {
    int i = blockIdx.x * blockDim.x + threadIdx.x;
    if (i < N_NODES) {
        int d = offsets[i + 1] - offsets[i];
        rinv[i] = 1.0f / (float)max(d, 1);
    }
}

// ---------------- converts ----------------

__global__ void conv_x_kernel(const float* __restrict__ x, ushort_t* __restrict__ xb) {
    int tid = blockIdx.x * blockDim.x + threadIdx.x;   // N_NODES*32
    int row = tid >> 5, c = (tid & 31) * 4;
    float4 v = *(const float4*)(x + (size_t)row * FEAT + c);
    ushort4 o;
    o.x = f2b(v.x); o.y = f2b(v.y); o.z = f2b(v.z); o.w = f2b(v.w);
    *(ushort4*)(xb + (size_t)row * (2 * FEAT) + c) = o;
}

// Wt[n][k] = (k<K1 ? W0[k][n] : W1[k-K1][n]) as bf16; K = 2*K1 = 1<<kbits
__global__ void conv_wt_kernel(const float* __restrict__ W0, const float* __restrict__ W1,
                               int K1, int N, int kbits, ushort_t* __restrict__ Wt) {
    int tid = blockIdx.x * blockDim.x + threadIdx.x;
    int K = 1 << kbits;
    if (tid >= N * K) return;
    int n = tid >> kbits, k = tid & (K - 1);
    float v = (k < K1) ? W0[(size_t)k * N + n] : W1[(size_t)(k - K1) * N + n];
    Wt[tid] = f2b(v);
}

// ---------------- CSR gathers (bf16 in/out, fp32 accum) ----------------
__global__ __launch_bounds__(256) void gather1_kernel(
    const int* __restrict__ offsets, const int* __restrict__ srcbuf,
    const float* __restrict__ rinv, ushort_t* __restrict__ xb)
{
    int node = blockIdx.x * 4 + (threadIdx.x >> 6);
    if (node >= N_NODES) return;
    int lane = threadIdx.x & 63;
    int beg = offsets[node], end = offsets[node + 1];
    float a0 = 0.f, a1 = 0.f, b0 = 0.f, b1 = 0.f;
    float c0 = 0.f, c1 = 0.f, d0 = 0.f, d1 = 0.f;
    int j = beg;
    for (; j + 4 <= end; j += 4) {
        int s0 = srcbuf[j], s1 = srcbuf[j + 1], s2 = srcbuf[j + 2], s3 = srcbuf[j + 3];
        uint32 u0 = *(const uint32*)(xb + (size_t)s0 * 256 + lane * 2);
        uint32 u1 = *(const uint32*)(xb + (size_t)s1 * 256 + lane * 2);
        uint32 u2 = *(const uint32*)(xb + (size_t)s2 * 256 + lane * 2);
        uint32 u3 = *(const uint32*)(xb + (size_t)s3 * 256 + lane * 2);
        a0 += b2f((ushort_t)(u0 & 0xffff)); a1 += b2f((ushort_t)(u0 >> 16));
        b0 += b2f((ushort_t)(u1 & 0xffff)); b1 += b2f((ushort_t)(u1 >> 16));
        c0 += b2f((ushort_t)(u2 & 0xffff)); c1 += b2f((ushort_t)(u2 >> 16));
        d0 += b2f((ushort_t)(u3 & 0xffff)); d1 += b2f((ushort_t)(u3 >> 16));
    }
    for (; j < end; ++j) {
        uint32 u = *(const uint32*)(xb + (size_t)srcbuf[j] * 256 + lane * 2);
        a0 += b2f((ushort_t)(u & 0xffff)); a1 += b2f((ushort_t)(u >> 16));
    }
    float ri = rinv[node];
    uint32 o = (uint32)f2b((a0 + b0 + c0 + d0) * ri)
             | ((uint32)f2b((a1 + b1 + c1 + d1) * ri) << 16);
    *(uint32*)(xb + (size_t)node * 256 + 128 + lane * 2) = o;
}

__global__ __launch_bounds__(256) void gather2_kernel(
    const int* __restrict__ offsets, const int* __restrict__ srcbuf,
    const float* __restrict__ rinv, ushort_t* __restrict__ h1b)
{
    int node = blockIdx.x * 4 + (threadIdx.x >> 6);
    if (node >= N_NODES) return;
    int lane = threadIdx.x & 63;
    int beg = offsets[node], end = offsets[node + 1];
    float s[4] = {0.f, 0.f, 0.f, 0.f};
    float t[4] = {0.f, 0.f, 0.f, 0.f};
    float u[4] = {0.f, 0.f, 0.f, 0.f};
    float v[4] = {0.f, 0.f, 0.f, 0.f};
    int j = beg;
    for (; j + 4 <= end; j += 4) {
        int s0 = srcbuf[j], s1 = srcbuf[j + 1], s2 = srcbuf[j + 2], s3 = srcbuf[j + 3];
        uint2 u0 = *(const uint2*)(h1b + (size_t)s0 * 512 + lane * 4);
        uint2 u1 = *(const uint2*)(h1b + (size_t)s1 * 512 + lane * 4);
        uint2 u2 = *(const uint2*)(h1b + (size_t)s2 * 512 + lane * 4);
        uint2 u3 = *(const uint2*)(h1b + (size_t)s3 * 512 + lane * 4);
        s[0] += b2f((ushort_t)(u0.x & 0xffff)); s[1] += b2f((ushort_t)(u0.x >> 16));
        s[2] += b2f((ushort_t)(u0.y & 0xffff)); s[3] += b2f((ushort_t)(u0.y >> 16));
        t[0] += b2f((ushort_t)(u1.x & 0xffff)); t[1] += b2f((ushort_t)(u1.x >> 16));
        t[2] += b2f((ushort_t)(u1.y & 0xffff)); t[3] += b2f((ushort_t)(u1.y >> 16));
        u[0] += b2f((ushort_t)(u2.x & 0xffff)); u[1] += b2f((ushort_t)(u2.x >> 16));
        u[2] += b2f((ushort_t)(u2.y & 0xffff)); u[3] += b2f((ushort_t)(u2.y >> 16));
        v[0] += b2f((ushort_t)(u3.x & 0xffff)); v[1] += b2f((ushort_t)(u3.x >> 16));
        v[2] += b2f((ushort_t)(u3.y & 0xffff)); v[3] += b2f((ushort_t)(u3.y >> 16));
    }
    for (; j < end; ++j) {
        uint2 uu = *(const uint2*)(h1b + (size_t)srcbuf[j] * 512 + lane * 4);
        s[0] += b2f((ushort_t)(uu.x & 0xffff)); s[1] += b2f((ushort_t)(uu.x >> 16));
        s[2] += b2f((ushort_t)(uu.y & 0xffff)); s[3] += b2f((ushort_t)(uu.y >> 16));
    }
    float ri = rinv[node];
    uint2 o;
    o.x = (uint32)f2b((s[0] + t[0] + u[0] + v[0]) * ri)
        | ((uint32)f2b((s[1] + t[1] + u[1] + v[1]) * ri) << 16);
    o.y = (uint32)f2b((s[2] + t[2] + u[2] + v[2]) * ri)
        | ((uint32)f2b((s[3] + t[3] + u[3] + v[3]) * ri) << 16);
    *(uint2*)(h1b + (size_t)node * 512 + 256 + lane * 4) = o;
}

// ---------------- bf16 MFMA GEMM (128x128 tile, BK=32, XOR-swizzled LDS) ----------------
template<int KTOT, int OUTSTR, bool POOL>
__global__ __launch_bounds__(256) void mfma_gemm(
    const ushort_t* __restrict__ A, const ushort_t* __restrict__ Bt,
    const float* __restrict__ bias,
    ushort_t* __restrict__ outb, float* __restrict__ psum,
    const int* __restrict__ batch)
{
    __shared__ ushort_t As[4096];       // [128 rows][32 k], chunk-swizzled
    __shared__ ushort_t Bs[4096];       // [128 n][32 k], chunk-swizzled
    __shared__ float pool2[8 * 128];    // POOL reduction scratch (4 KB)

    const int tid = threadIdx.x;
    const int lane = tid & 63;
    const int wave = tid >> 6;
    const int quad = lane >> 4;
    const int l16 = lane & 15;
    const int m0w = (wave & 1) * 64;
    const int n0w = (wave >> 1) * 64;
    const int row0 = blockIdx.y * 128;
    const int col0 = blockIdx.x * 128;
    const int Mm1 = N_NODES - 1;

    const int sw = (l16 >> 1) & 3;
    const int co = (quad ^ sw) * 8;

    int st_r[2], st_cb[2];
    #pragma unroll
    for (int c = 0; c < 2; ++c) {
        int idx = c * 256 + tid;
        int r = idx >> 2;
        int q = idx & 3;
        st_r[c] = r;
        st_cb[c] = (q ^ ((r >> 1) & 3)) * 8;
    }

    floatx4 acc[4][4] = {};

    for (int kt = 0; kt < KTOT / 32; ++kt) {
        const int kb = kt * 32;
        #pragma unroll
        for (int c = 0; c < 2; ++c) {
            async16(A + (size_t)min(row0 + st_r[c], Mm1) * KTOT + kb + st_cb[c],
                    &As[(c * 4 + wave) * 512]);
        }
        #pragma unroll
        for (int c = 0; c < 2; ++c) {
            async16(Bt + (size_t)(col0 + st_r[c]) * KTOT + kb + st_cb[c],
                    &Bs[(c * 4 + wave) * 512]);
        }
        __syncthreads();
        short8 a[4], b[4];
        #pragma unroll
        for (int t = 0; t < 4; ++t)
            a[t] = *(const short8*)&As[(m0w + t * 16 + l16) * 32 + co];
        #pragma unroll
        for (int t = 0; t < 4; ++t)
            b[t] = *(const short8*)&Bs[(n0w + t * 16 + l16) * 32 + co];
        #pragma unroll
        for (int i = 0; i < 4; ++i)
            #pragma unroll
            for (int j = 0; j < 4; ++j)
                acc[i][j] = __builtin_amdgcn_mfma_f32_16x16x32_bf16(a[i], b[j], acc[i][j], 0, 0, 0);
        __syncthreads();
    }

    float bias4[4];
    #pragma unroll
    for (int j = 0; j < 4; ++j) bias4[j] = bias[col0 + n0w + j * 16 + l16];

    if (!POOL) {
        #pragma unroll
        for (int i = 0; i < 4; ++i) {
            #pragma unroll
            for (int r = 0; r < 4; ++r) {
                int m = row0 + m0w + i * 16 + quad * 4 + r;
                if (m < N_NODES) {
                    #pragma unroll
                    for (int j = 0; j < 4; ++j) {
                        float v = fmaxf(acc[i][j][r] + bias4[j], 0.f);
                        outb[(size_t)m * OUTSTR + col0 + n0w + j * 16 + l16] = f2b(v);
                    }
                }
            }
        }
    } else {
        int gmin = batch[row0];
        int gmax = batch[min(row0 + 127, N_NODES - 1)];
        int span = gmax - gmin + 1;
        if (span == 1) {
            float s[4] = {0.f, 0.f, 0.f, 0.f};
            #pragma unroll
            for (int i = 0; i < 4; ++i) {
                #pragma unroll
                for (int r = 0; r < 4; ++r) {
                    int m = row0 + m0w + i * 16 + quad * 4 + r;
                    if (m < N_NODES) {
                        #pragma unroll
                        for (int j = 0; j < 4; ++j)
                            s[j] += fmaxf(acc[i][j][r] + bias4[j], 0.f);
                    }
                }
            }
            int slot = (wave & 1) * 4 + quad;
            #pragma unroll
            for (int j = 0; j < 4; ++j)
                pool2[slot * 128 + n0w + j * 16 + l16] = s[j];
            __syncthreads();
            if (tid < 128) {
                float v = 0.f;
                #pragma unroll
                for (int k = 0; k < 8; ++k) v += pool2[k * 128 + tid];
                atomicAdd(psum + (size_t)gmin * HID + col0 + tid, v);
            }
        } else if (span <= 8) {
            for (int i = tid; i < span * 128; i += 256) pool2[i] = 0.f;
            __syncthreads();
            float s[4] = {0.f, 0.f, 0.f, 0.f};
            int cg = -1;
            #pragma unroll
            for (int i = 0; i < 4; ++i) {
                #pragma unroll
                for (int r = 0; r < 4; ++r) {
                    int m = row0 + m0w + i * 16 + quad * 4 + r;
                    if (m < N_NODES) {
                        int g = batch[m] - gmin;
                        if (g != cg) {
                            if (cg >= 0) {
                                #pragma unroll
                                for (int j = 0; j < 4; ++j)
                                    atomicAdd(&pool2[cg * 128 + n0w + j * 16 + l16], s[j]);
                            }
                            cg = g;
                            s[0] = s[1] = s[2] = s[3] = 0.f;
                        }
                        #pragma unroll
                        for (int j = 0; j < 4; ++j)
                            s[j] += fmaxf(acc[i][j][r] + bias4[j], 0.f);
                    }
                }
            }
            if (cg >= 0) {
                #pragma unroll
                for (int j = 0; j < 4; ++j)
                    atomicAdd(&pool2[cg * 128 + n0w + j * 16 + l16], s[j]);
            }
            __syncthreads();
            for (int i = tid; i < span * 128; i += 256) {
                float v = pool2[i];
                if (v != 0.f)
                    atomicAdd(psum + (size_t)(gmin + (i >> 7)) * HID + col0 + (i & 127), v);
            }
        } else {
            #pragma unroll
            for (int i = 0; i < 4; ++i) {
                #pragma unroll
                for (int r = 0; r < 4; ++r) {
                    int m = row0 + m0w + i * 16 + quad * 4 + r;
                    if (m < N_NODES) {
                        int g = batch[m];
                        #pragma unroll
                        for (int j = 0; j < 4; ++j) {
                            float v = fmaxf(acc[i][j][r] + bias4[j], 0.f);
                            atomicAdd(psum + (size_t)g * HID + col0 + n0w + j * 16 + l16, v);
                        }
                    }
                }
            }
        }
    }
}

// ---------------- head ----------------
__global__ __launch_bounds__(512) void head_kernel(
    const float* __restrict__ psum, const float* __restrict__ ncnt,
    const float* __restrict__ Wh, const float* __restrict__ bh,
    const float* __restrict__ Wc, const float* __restrict__ bc,
    const float* __restrict__ Wout, const float* __restrict__ bout,
    float* __restrict__ out)
{
    __shared__ float p[HID];
    __shared__ float hrow[HID];
    __shared__ float redm[8];
    __shared__ float reds[8];
    __shared__ float bm, bs;

    const int g = blockIdx.x;
    const int j = threadIdx.x;

    float inv = 1.0f / fmaxf(ncnt[g], 1.0f);
    p[j] = psum[(size_t)g * HID + j] * inv;
    __syncthreads();

    float h = bh[j], c = bc[j];
    for (int k = 0; k < HID; ++k) {
        float pk = p[k];
        h += pk * Wh[(size_t)k * HID + j];
        c += pk * Wc[(size_t)k * HID + j];
    }
    out[(size_t)N_GRAPHS * VOCAB + (size_t)g * HID + j] = h;       // hidden
    out[(size_t)2 * N_GRAPHS * VOCAB + (size_t)g * HID + j] = c;   // cell
    hrow[j] = h;
    __syncthreads();

    float l = bout[j];
    for (int k = 0; k < HID; ++k) l += hrow[k] * Wout[(size_t)k * VOCAB + j];

    const int lane = j & 63, wave = j >> 6;
    float m = l;
    #pragma unroll
    for (int o = 32; o > 0; o >>= 1) m = fmaxf(m, __shfl_down(m, o));
    if (lane == 0) redm[wave] = m;
    __syncthreads();
    if (j == 0) {
        float mm = redm[0];
        for (int w = 1; w < 8; ++w) mm = fmaxf(mm, redm[w]);
        bm = mm;
    }
    __syncthreads();
    m = bm;
    float e = __expf(l - m);
    float s = e;
    #pragma unroll
    for (int o = 32; o > 0; o >>= 1) s += __shfl_down(s, o);
    if (lane == 0) reds[wave] = s;
    __syncthreads();
    if (j == 0) {
        float ss = 0.f;
        for (int w = 0; w < 8; ++w) ss += reds[w];
        bs = ss;
    }
    __syncthreads();
    out[(size_t)g * VOCAB + j] = l - m - logf(bs);                  // logits
}

// ---------------- launch ----------------
extern "C" void kernel_launch(void* const* d_in, const int* in_sizes, int n_in,
                              void* d_out, int out_size, void* d_ws, size_t ws_size,
                              hipStream_t stream) {
    const float* x      = (const float*)d_in[1];
    const int*   edge   = (const int*)d_in[2];
    const int*   batch  = (const int*)d_in[3];
    const float* Wroot1 = (const float*)d_in[4];
    const float* Wrel1  = (const float*)d_in[5];
    const float* b1     = (const float*)d_in[6];
    const float* Wroot2 = (const float*)d_in[7];
    const float* Wrel2  = (const float*)d_in[8];
    const float* b2     = (const float*)d_in[9];
    const float* Wh     = (const float*)d_in[10];
    const float* bh     = (const float*)d_in[11];
    const float* Wc     = (const float*)d_in[12];
    const float* bc     = (const float*)d_in[13];
    const float* Wout   = (const float*)d_in[14];
    const float* bout   = (const float*)d_in[15];
    float* out = (float*)d_out;

    // workspace layout
    int*      deg_i   = (int*)d_ws;                        // 50000 (zeroed)
    int*      cursor  = deg_i + N_NODES;                   // 50000 (zeroed)
    float*    ncnt    = (float*)(cursor + N_NODES);        // 64    (zeroed)
    float*    psum    = ncnt + N_GRAPHS;                   // 32768 (zeroed)
    int*      offsets = (int*)(psum + N_GRAPHS * HID);     // 50001
    int*      srcbuf  = offsets + (N_NODES + 1);           // 800000
    float*    rinv    = (float*)(srcbuf + N_EDGES);        // 50000 (+3 pad)
    ushort_t* xb      = (ushort_t*)(rinv + N_NODES + 3);   // 50000*256 bf16
    ushort_t* h1b     = xb + (size_t)N_NODES * 256;        // 50000*512 bf16
    ushort_t* w1t     = h1b + (size_t)N_NODES * 512;       // 256*256
    ushort_t* w2t     = w1t + 256 * 256;                   // 512*512

    const size_t zero_bytes = (size_t)(2 * N_NODES + N_GRAPHS + N_GRAPHS * HID) * 4;
    hipMemsetAsync(d_ws, 0, zero_bytes, stream);

    deg_kernel<<<(N_EDGES + 255) / 256, 256, 0, stream>>>(edge, deg_i);
    ncnt_bs_kernel<<<1, 64, 0, stream>>>(batch, ncnt);
    scan_kernel<<<1, 1024, 0, stream>>>(deg_i, offsets);
    fill_kernel<<<(N_EDGES + 255) / 256, 256, 0, stream>>>(edge, offsets, cursor, srcbuf);
    rinv_kernel<<<(N_NODES + 255) / 256, 256, 0, stream>>>(offsets, rinv);

    conv_x_kernel<<<(N_NODES * 32) / 256, 256, 0, stream>>>(x, xb);
    conv_wt_kernel<<<(256 * 256) / 256, 256, 0, stream>>>(Wroot1, Wrel1, FEAT, EMB, 8, w1t);
    conv_wt_kernel<<<(512 * 512) / 256, 256, 0, stream>>>(Wroot2, Wrel2, EMB, HID, 9, w2t);

    gather1_kernel<<<(N_NODES + 3) / 4, 256, 0, stream>>>(offsets, srcbuf, rinv, xb);

    {   // layer 1: A=xb [50000 x 256] bf16, Wt=w1t [256 x 256] -> h1b cols 0..255
        dim3 grid(EMB / 128, (N_NODES + 127) / 128);
        mfma_gemm<256, 512, false><<<grid, 256, 0, stream>>>(
            xb, w1t, b1, h1b, nullptr, nullptr);
    }

    gather2_kernel<<<(N_NODES + 3) / 4, 256, 0, stream>>>(offsets, srcbuf, rinv, h1b);

    {   // layer 2: A=h1b [50000 x 512] bf16, Wt=w2t [512 x 512] -> pooled psum
        dim3 grid(HID / 128, (N_NODES + 127) / 128);
        mfma_gemm<512, 512, true><<<grid, 256, 0, stream>>>(
            h1b, w2t, b2, nullptr, psum, batch);
    }

    head_kernel<<<N_GRAPHS, 512, 0, stream>>>(psum, ncnt, Wh, bh, Wc, bc, Wout, bout, out);
}

// Round 6
// 445.993 us; speedup vs baseline: 12.4155x; 1.1541x over previous
//
#include <hip/hip_runtime.h>
#include <hip/hip_bf16.h>

#define N_NODES 50000
#define N_EDGES 800000
#define N_GRAPHS 64
#define FEAT 128
#define EMB 256
#define HID 512
#define VOCAB 512

#define SCAN_B 256
#define SCAN_NB ((N_NODES + SCAN_B - 1) / SCAN_B)   // 196

typedef __attribute__((ext_vector_type(8))) short short8;
typedef __attribute__((ext_vector_type(4))) float floatx4;
typedef unsigned short ushort_t;
typedef unsigned int uint32;

__device__ __forceinline__ ushort_t f2b(float f) {
    uint32 u = __builtin_bit_cast(uint32, f);
    u += 0x7fffu + ((u >> 16) & 1u);
    return (ushort_t)(u >> 16);
}
__device__ __forceinline__ float b2f(ushort_t h) {
    uint32 u = ((uint32)h) << 16;
    return __builtin_bit_cast(float, u);
}
__device__ __forceinline__ void async16(const void* g, void* l) {
    __builtin_amdgcn_global_load_lds(
        (const __attribute__((address_space(1))) void*)g,
        (__attribute__((address_space(3))) void*)l, 16, 0, 0);
}

// ---------------- CSR build ----------------

__global__ void deg_kernel(const int* __restrict__ edge, int* __restrict__ deg) {
    int e = blockIdx.x * blockDim.x + threadIdx.x;
    if (e < N_EDGES) atomicAdd(deg + edge[N_EDGES + e], 1);
}

// batch is sorted: ncnt[g] = lower_bound(g+1) - lower_bound(g). one block, 64 threads.
__global__ void ncnt_bs_kernel(const int* __restrict__ batch, float* __restrict__ ncnt) {
    int g = threadIdx.x;
    if (g >= N_GRAPHS) return;
    int lo = 0, hi = N_NODES;
    while (lo < hi) { int mid = (lo + hi) >> 1; if (batch[mid] < g) lo = mid + 1; else hi = mid; }
    int lo2 = lo, hi2 = N_NODES;
    while (lo2 < hi2) { int mid = (lo2 + hi2) >> 1; if (batch[mid] < g + 1) lo2 = mid + 1; else hi2 = mid; }
    ncnt[g] = (float)(lo2 - lo);
}

// ---- 3-phase parallel exclusive scan of deg -> offsets ----
__global__ __launch_bounds__(SCAN_B) void scan_part_kernel(const int* __restrict__ deg,
                                                           int* __restrict__ blocksum) {
    __shared__ int s[SCAN_B];
    int i = blockIdx.x * SCAN_B + threadIdx.x;
    int t = threadIdx.x;
    s[t] = (i < N_NODES) ? deg[i] : 0;
    __syncthreads();
    #pragma unroll
    for (int off = SCAN_B / 2; off > 0; off >>= 1) {
        if (t < off) s[t] += s[t + off];
        __syncthreads();
    }
    if (t == 0) blocksum[blockIdx.x] = s[0];
}

__global__ __launch_bounds__(SCAN_B) void scan_base_kernel(const int* __restrict__ blocksum,
                                                           int* __restrict__ blockbase) {
    __shared__ int s[SCAN_B];
    int t = threadIdx.x;
    int v = (t < SCAN_NB) ? blocksum[t] : 0;
    s[t] = v;
    __syncthreads();
    #pragma unroll
    for (int off = 1; off < SCAN_B; off <<= 1) {
        int u = (t >= off) ? s[t - off] : 0;
        __syncthreads();
        s[t] += u;
        __syncthreads();
    }
    blockbase[t] = s[t] - v;   // exclusive
}

__global__ __launch_bounds__(SCAN_B) void scan_final_kernel(const int* __restrict__ deg,
                                                            const int* __restrict__ blockbase,
                                                            int* __restrict__ offsets) {
    __shared__ int s[SCAN_B];
    int i = blockIdx.x * SCAN_B + threadIdx.x;
    int t = threadIdx.x;
    int v = (i < N_NODES) ? deg[i] : 0;
    s[t] = v;
    __syncthreads();
    #pragma unroll
    for (int off = 1; off < SCAN_B; off <<= 1) {
        int u = (t >= off) ? s[t - off] : 0;
        __syncthreads();
        s[t] += u;
        __syncthreads();
    }
    int excl = s[t] - v + blockbase[blockIdx.x];
    if (i < N_NODES) offsets[i] = excl;
    if (i == N_NODES - 1) offsets[N_NODES] = excl + v;
}

__global__ void fill_kernel(const int* __restrict__ edge, const int* __restrict__ offsets,
                            int* __restrict__ cursor, int* __restrict__ srcbuf) {
    int e = blockIdx.x * blockDim.x + threadIdx.x;
    if (e < N_EDGES) {
        int src = edge[e];
        int dst = edge[N_EDGES + e];
        int pos = atomicAdd(cursor + dst, 1);
        srcbuf[offsets[dst] + pos] = src;
    }
}

__global__ void rinv_kernel(const int* __restrict__ offsets, float* __restrict__ rinv) {
    int i = blockIdx.x * blockDim.x + threadIdx.x;
    if (i < N_NODES) {
        int d = offsets[i + 1] - offsets[i];
        rinv[i] = 1.0f / (float)max(d, 1);
    }
}

// ---------------- converts ----------------

__global__ void conv_x_kernel(const float* __restrict__ x, ushort_t* __restrict__ xb) {
    int tid = blockIdx.x * blockDim.x + threadIdx.x;   // N_NODES*32
    int row = tid >> 5, c = (tid & 31) * 4;
    float4 v = *(const float4*)(x + (size_t)row * FEAT + c);
    ushort4 o;
    o.x = f2b(v.x); o.y = f2b(v.y); o.z = f2b(v.z); o.w = f2b(v.w);
    *(ushort4*)(xb + (size_t)row * (2 * FEAT) + c) = o;
}

// Wt[n][k] = (k<K1 ? W0[k][n] : W1[k-K1][n]) as bf16; K = 2*K1 = 1<<kbits
__global__ void conv_wt_kernel(const float* __restrict__ W0, const float* __restrict__ W1,
                               int K1, int N, int kbits, ushort_t* __restrict__ Wt) {
    int tid = blockIdx.x * blockDim.x + threadIdx.x;
    int K = 1 << kbits;
    if (tid >= N * K) return;
    int n = tid >> kbits, k = tid & (K - 1);
    float v = (k < K1) ? W0[(size_t)k * N + n] : W1[(size_t)(k - K1) * N + n];
    Wt[tid] = f2b(v);
}

// ---------------- CSR gathers (bf16 in/out, fp32 accum) ----------------
__global__ __launch_bounds__(256) void gather1_kernel(
    const int* __restrict__ offsets, const int* __restrict__ srcbuf,
    const float* __restrict__ rinv, ushort_t* __restrict__ xb)
{
    int node = blockIdx.x * 4 + (threadIdx.x >> 6);
    if (node >= N_NODES) return;
    int lane = threadIdx.x & 63;
    int beg = offsets[node], end = offsets[node + 1];
    float a0 = 0.f, a1 = 0.f, b0 = 0.f, b1 = 0.f;
    float c0 = 0.f, c1 = 0.f, d0 = 0.f, d1 = 0.f;
    int j = beg;
    for (; j + 4 <= end; j += 4) {
        int s0 = srcbuf[j], s1 = srcbuf[j + 1], s2 = srcbuf[j + 2], s3 = srcbuf[j + 3];
        uint32 u0 = *(const uint32*)(xb + (size_t)s0 * 256 + lane * 2);
        uint32 u1 = *(const uint32*)(xb + (size_t)s1 * 256 + lane * 2);
        uint32 u2 = *(const uint32*)(xb + (size_t)s2 * 256 + lane * 2);
        uint32 u3 = *(const uint32*)(xb + (size_t)s3 * 256 + lane * 2);
        a0 += b2f((ushort_t)(u0 & 0xffff)); a1 += b2f((ushort_t)(u0 >> 16));
        b0 += b2f((ushort_t)(u1 & 0xffff)); b1 += b2f((ushort_t)(u1 >> 16));
        c0 += b2f((ushort_t)(u2 & 0xffff)); c1 += b2f((ushort_t)(u2 >> 16));
        d0 += b2f((ushort_t)(u3 & 0xffff)); d1 += b2f((ushort_t)(u3 >> 16));
    }
    for (; j < end; ++j) {
        uint32 u = *(const uint32*)(xb + (size_t)srcbuf[j] * 256 + lane * 2);
        a0 += b2f((ushort_t)(u & 0xffff)); a1 += b2f((ushort_t)(u >> 16));
    }
    float ri = rinv[node];
    uint32 o = (uint32)f2b((a0 + b0 + c0 + d0) * ri)
             | ((uint32)f2b((a1 + b1 + c1 + d1) * ri) << 16);
    *(uint32*)(xb + (size_t)node * 256 + 128 + lane * 2) = o;
}

__global__ __launch_bounds__(256) void gather2_kernel(
    const int* __restrict__ offsets, const int* __restrict__ srcbuf,
    const float* __restrict__ rinv, ushort_t* __restrict__ h1b)
{
    int node = blockIdx.x * 4 + (threadIdx.x >> 6);
    if (node >= N_NODES) return;
    int lane = threadIdx.x & 63;
    int beg = offsets[node], end = offsets[node + 1];
    float s[4] = {0.f, 0.f, 0.f, 0.f};
    float t[4] = {0.f, 0.f, 0.f, 0.f};
    float u[4] = {0.f, 0.f, 0.f, 0.f};
    float v[4] = {0.f, 0.f, 0.f, 0.f};
    int j = beg;
    for (; j + 4 <= end; j += 4) {
        int s0 = srcbuf[j], s1 = srcbuf[j + 1], s2 = srcbuf[j + 2], s3 = srcbuf[j + 3];
        uint2 u0 = *(const uint2*)(h1b + (size_t)s0 * 512 + lane * 4);
        uint2 u1 = *(const uint2*)(h1b + (size_t)s1 * 512 + lane * 4);
        uint2 u2 = *(const uint2*)(h1b + (size_t)s2 * 512 + lane * 4);
        uint2 u3 = *(const uint2*)(h1b + (size_t)s3 * 512 + lane * 4);
        s[0] += b2f((ushort_t)(u0.x & 0xffff)); s[1] += b2f((ushort_t)(u0.x >> 16));
        s[2] += b2f((ushort_t)(u0.y & 0xffff)); s[3] += b2f((ushort_t)(u0.y >> 16));
        t[0] += b2f((ushort_t)(u1.x & 0xffff)); t[1] += b2f((ushort_t)(u1.x >> 16));
        t[2] += b2f((ushort_t)(u1.y & 0xffff)); t[3] += b2f((ushort_t)(u1.y >> 16));
        u[0] += b2f((ushort_t)(u2.x & 0xffff)); u[1] += b2f((ushort_t)(u2.x >> 16));
        u[2] += b2f((ushort_t)(u2.y & 0xffff)); u[3] += b2f((ushort_t)(u2.y >> 16));
        v[0] += b2f((ushort_t)(u3.x & 0xffff)); v[1] += b2f((ushort_t)(u3.x >> 16));
        v[2] += b2f((ushort_t)(u3.y & 0xffff)); v[3] += b2f((ushort_t)(u3.y >> 16));
    }
    for (; j < end; ++j) {
        uint2 uu = *(const uint2*)(h1b + (size_t)srcbuf[j] * 512 + lane * 4);
        s[0] += b2f((ushort_t)(uu.x & 0xffff)); s[1] += b2f((ushort_t)(uu.x >> 16));
        s[2] += b2f((ushort_t)(uu.y & 0xffff)); s[3] += b2f((ushort_t)(uu.y >> 16));
    }
    float ri = rinv[node];
    uint2 o;
    o.x = (uint32)f2b((s[0] + t[0] + u[0] + v[0]) * ri)
        | ((uint32)f2b((s[1] + t[1] + u[1] + v[1]) * ri) << 16);
    o.y = (uint32)f2b((s[2] + t[2] + u[2] + v[2]) * ri)
        | ((uint32)f2b((s[3] + t[3] + u[3] + v[3]) * ri) << 16);
    *(uint2*)(h1b + (size_t)node * 512 + 256 + lane * 4) = o;
}

// ---------------- bf16 MFMA GEMM (128x128 tile, BK=32, XOR-swizzled LDS) ----------------
template<int KTOT, int OUTSTR, bool POOL>
__global__ __launch_bounds__(256) void mfma_gemm(
    const ushort_t* __restrict__ A, const ushort_t* __restrict__ Bt,
    const float* __restrict__ bias,
    ushort_t* __restrict__ outb, float* __restrict__ psum,
    const int* __restrict__ batch)
{
    __shared__ ushort_t As[4096];       // [128 rows][32 k], chunk-swizzled
    __shared__ ushort_t Bs[4096];       // [128 n][32 k], chunk-swizzled
    __shared__ float pool2[8 * 128];    // POOL reduction scratch (4 KB)

    const int tid = threadIdx.x;
    const int lane = tid & 63;
    const int wave = tid >> 6;
    const int quad = lane >> 4;
    const int l16 = lane & 15;
    const int m0w = (wave & 1) * 64;
    const int n0w = (wave >> 1) * 64;
    const int row0 = blockIdx.y * 128;
    const int col0 = blockIdx.x * 128;
    const int Mm1 = N_NODES - 1;

    const int sw = (l16 >> 1) & 3;
    const int co = (quad ^ sw) * 8;

    int st_r[2], st_cb[2];
    #pragma unroll
    for (int c = 0; c < 2; ++c) {
        int idx = c * 256 + tid;
        int r = idx >> 2;
        int q = idx & 3;
        st_r[c] = r;
        st_cb[c] = (q ^ ((r >> 1) & 3)) * 8;
    }

    floatx4 acc[4][4] = {};

    for (int kt = 0; kt < KTOT / 32; ++kt) {
        const int kb = kt * 32;
        #pragma unroll
        for (int c = 0; c < 2; ++c) {
            async16(A + (size_t)min(row0 + st_r[c], Mm1) * KTOT + kb + st_cb[c],
                    &As[(c * 4 + wave) * 512]);
        }
        #pragma unroll
        for (int c = 0; c < 2; ++c) {
            async16(Bt + (size_t)(col0 + st_r[c]) * KTOT + kb + st_cb[c],
                    &Bs[(c * 4 + wave) * 512]);
        }
        __syncthreads();
        short8 a[4], b[4];
        #pragma unroll
        for (int t = 0; t < 4; ++t)
            a[t] = *(const short8*)&As[(m0w + t * 16 + l16) * 32 + co];
        #pragma unroll
        for (int t = 0; t < 4; ++t)
            b[t] = *(const short8*)&Bs[(n0w + t * 16 + l16) * 32 + co];
        #pragma unroll
        for (int i = 0; i < 4; ++i)
            #pragma unroll
            for (int j = 0; j < 4; ++j)
                acc[i][j] = __builtin_amdgcn_mfma_f32_16x16x32_bf16(a[i], b[j], acc[i][j], 0, 0, 0);
        __syncthreads();
    }

    float bias4[4];
    #pragma unroll
    for (int j = 0; j < 4; ++j) bias4[j] = bias[col0 + n0w + j * 16 + l16];

    if (!POOL) {
        #pragma unroll
        for (int i = 0; i < 4; ++i) {
            #pragma unroll
            for (int r = 0; r < 4; ++r) {
                int m = row0 + m0w + i * 16 + quad * 4 + r;
                if (m < N_NODES) {
                    #pragma unroll
                    for (int j = 0; j < 4; ++j) {
                        float v = fmaxf(acc[i][j][r] + bias4[j], 0.f);
                        outb[(size_t)m * OUTSTR + col0 + n0w + j * 16 + l16] = f2b(v);
                    }
                }
            }
        }
    } else {
        int gmin = batch[row0];
        int gmax = batch[min(row0 + 127, N_NODES - 1)];
        int span = gmax - gmin + 1;
        if (span == 1) {
            float s[4] = {0.f, 0.f, 0.f, 0.f};
            #pragma unroll
            for (int i = 0; i < 4; ++i) {
                #pragma unroll
                for (int r = 0; r < 4; ++r) {
                    int m = row0 + m0w + i * 16 + quad * 4 + r;
                    if (m < N_NODES) {
                        #pragma unroll
                        for (int j = 0; j < 4; ++j)
                            s[j] += fmaxf(acc[i][j][r] + bias4[j], 0.f);
                    }
                }
            }
            int slot = (wave & 1) * 4 + quad;
            #pragma unroll
            for (int j = 0; j < 4; ++j)
                pool2[slot * 128 + n0w + j * 16 + l16] = s[j];
            __syncthreads();
            if (tid < 128) {
                float v = 0.f;
                #pragma unroll
                for (int k = 0; k < 8; ++k) v += pool2[k * 128 + tid];
                atomicAdd(psum + (size_t)gmin * HID + col0 + tid, v);
            }
        } else if (span <= 8) {
            for (int i = tid; i < span * 128; i += 256) pool2[i] = 0.f;
            __syncthreads();
            float s[4] = {0.f, 0.f, 0.f, 0.f};
            int cg = -1;
            #pragma unroll
            for (int i = 0; i < 4; ++i) {
                #pragma unroll
                for (int r = 0; r < 4; ++r) {
                    int m = row0 + m0w + i * 16 + quad * 4 + r;
                    if (m < N_NODES) {
                        int g = batch[m] - gmin;
                        if (g != cg) {
                            if (cg >= 0) {
                                #pragma unroll
                                for (int j = 0; j < 4; ++j)
                                    atomicAdd(&pool2[cg * 128 + n0w + j * 16 + l16], s[j]);
                            }
                            cg = g;
                            s[0] = s[1] = s[2] = s[3] = 0.f;
                        }
                        #pragma unroll
                        for (int j = 0; j < 4; ++j)
                            s[j] += fmaxf(acc[i][j][r] + bias4[j], 0.f);
                    }
                }
            }
            if (cg >= 0) {
                #pragma unroll
                for (int j = 0; j < 4; ++j)
                    atomicAdd(&pool2[cg * 128 + n0w + j * 16 + l16], s[j]);
            }
            __syncthreads();
            for (int i = tid; i < span * 128; i += 256) {
                float v = pool2[i];
                if (v != 0.f)
                    atomicAdd(psum + (size_t)(gmin + (i >> 7)) * HID + col0 + (i & 127), v);
            }
        } else {
            #pragma unroll
            for (int i = 0; i < 4; ++i) {
                #pragma unroll
                for (int r = 0; r < 4; ++r) {
                    int m = row0 + m0w + i * 16 + quad * 4 + r;
                    if (m < N_NODES) {
                        int g = batch[m];
                        #pragma unroll
                        for (int j = 0; j < 4; ++j) {
                            float v = fmaxf(acc[i][j][r] + bias4[j], 0.f);
                            atomicAdd(psum + (size_t)g * HID + col0 + n0w + j * 16 + l16, v);
                        }
                    }
                }
            }
        }
    }
}

// ---------------- head ----------------
__global__ __launch_bounds__(512) void head_kernel(
    const float* __restrict__ psum, const float* __restrict__ ncnt,
    const float* __restrict__ Wh, const float* __restrict__ bh,
    const float* __restrict__ Wc, const float* __restrict__ bc,
    const float* __restrict__ Wout, const float* __restrict__ bout,
    float* __restrict__ out)
{
    __shared__ float p[HID];
    __shared__ float hrow[HID];
    __shared__ float redm[8];
    __shared__ float reds[8];
    __shared__ float bm, bs;

    const int g = blockIdx.x;
    const int j = threadIdx.x;

    float inv = 1.0f / fmaxf(ncnt[g], 1.0f);
    p[j] = psum[(size_t)g * HID + j] * inv;
    __syncthreads();

    float h = bh[j], c = bc[j];
    for (int k = 0; k < HID; ++k) {
        float pk = p[k];
        h += pk * Wh[(size_t)k * HID + j];
        c += pk * Wc[(size_t)k * HID + j];
    }
    out[(size_t)N_GRAPHS * VOCAB + (size_t)g * HID + j] = h;       // hidden
    out[(size_t)2 * N_GRAPHS * VOCAB + (size_t)g * HID + j] = c;   // cell
    hrow[j] = h;
    __syncthreads();

    float l = bout[j];
    for (int k = 0; k < HID; ++k) l += hrow[k] * Wout[(size_t)k * VOCAB + j];

    const int lane = j & 63, wave = j >> 6;
    float m = l;
    #pragma unroll
    for (int o = 32; o > 0; o >>= 1) m = fmaxf(m, __shfl_down(m, o));
    if (lane == 0) redm[wave] = m;
    __syncthreads();
    if (j == 0) {
        float mm = redm[0];
        for (int w = 1; w < 8; ++w) mm = fmaxf(mm, redm[w]);
        bm = mm;
    }
    __syncthreads();
    m = bm;
    float e = __expf(l - m);
    float s = e;
    #pragma unroll
    for (int o = 32; o > 0; o >>= 1) s += __shfl_down(s, o);
    if (lane == 0) reds[wave] = s;
    __syncthreads();
    if (j == 0) {
        float ss = 0.f;
        for (int w = 0; w < 8; ++w) ss += reds[w];
        bs = ss;
    }
    __syncthreads();
    out[(size_t)g * VOCAB + j] = l - m - logf(bs);                  // logits
}

// ---------------- launch ----------------
extern "C" void kernel_launch(void* const* d_in, const int* in_sizes, int n_in,
                              void* d_out, int out_size, void* d_ws, size_t ws_size,
                              hipStream_t stream) {
    const float* x      = (const float*)d_in[1];
    const int*   edge   = (const int*)d_in[2];
    const int*   batch  = (const int*)d_in[3];
    const float* Wroot1 = (const float*)d_in[4];
    const float* Wrel1  = (const float*)d_in[5];
    const float* b1     = (const float*)d_in[6];
    const float* Wroot2 = (const float*)d_in[7];
    const float* Wrel2  = (const float*)d_in[8];
    const float* b2     = (const float*)d_in[9];
    const float* Wh     = (const float*)d_in[10];
    const float* bh     = (const float*)d_in[11];
    const float* Wc     = (const float*)d_in[12];
    const float* bc     = (const float*)d_in[13];
    const float* Wout   = (const float*)d_in[14];
    const float* bout   = (const float*)d_in[15];
    float* out = (float*)d_out;

    // workspace layout
    int*      deg_i   = (int*)d_ws;                        // 50000 (zeroed)
    int*      cursor  = deg_i + N_NODES;                   // 50000 (zeroed)
    float*    ncnt    = (float*)(cursor + N_NODES);        // 64    (zeroed)
    float*    psum    = ncnt + N_GRAPHS;                   // 32768 (zeroed)
    int*      offsets = (int*)(psum + N_GRAPHS * HID);     // 50001
    int*      srcbuf  = offsets + (N_NODES + 1);           // 800000
    int*      bsum    = srcbuf + N_EDGES;                  // 256
    int*      bbase   = bsum + 256;                        // 256
    float*    rinv    = (float*)(bbase + 256);             // 50000 (+3 pad)
    ushort_t* xb      = (ushort_t*)(rinv + N_NODES + 3);   // 50000*256 bf16
    ushort_t* h1b     = xb + (size_t)N_NODES * 256;        // 50000*512 bf16
    ushort_t* w1t     = h1b + (size_t)N_NODES * 512;       // 256*256
    ushort_t* w2t     = w1t + 256 * 256;                   // 512*512

    const size_t zero_bytes = (size_t)(2 * N_NODES + N_GRAPHS + N_GRAPHS * HID) * 4;
    hipMemsetAsync(d_ws, 0, zero_bytes, stream);

    deg_kernel<<<(N_EDGES + 255) / 256, 256, 0, stream>>>(edge, deg_i);
    ncnt_bs_kernel<<<1, 64, 0, stream>>>(batch, ncnt);
    scan_part_kernel<<<SCAN_NB, SCAN_B, 0, stream>>>(deg_i, bsum);
    scan_base_kernel<<<1, SCAN_B, 0, stream>>>(bsum, bbase);
    scan_final_kernel<<<SCAN_NB, SCAN_B, 0, stream>>>(deg_i, bbase, offsets);
    fill_kernel<<<(N_EDGES + 255) / 256, 256, 0, stream>>>(edge, offsets, cursor, srcbuf);
    rinv_kernel<<<(N_NODES + 255) / 256, 256, 0, stream>>>(offsets, rinv);

    conv_x_kernel<<<(N_NODES * 32) / 256, 256, 0, stream>>>(x, xb);
    conv_wt_kernel<<<(256 * 256) / 256, 256, 0, stream>>>(Wroot1, Wrel1, FEAT, EMB, 8, w1t);
    conv_wt_kernel<<<(512 * 512) / 256, 256, 0, stream>>>(Wroot2, Wrel2, EMB, HID, 9, w2t);

    gather1_kernel<<<(N_NODES + 3) / 4, 256, 0, stream>>>(offsets, srcbuf, rinv, xb);

    {   // layer 1: A=xb [50000 x 256] bf16, Wt=w1t [256 x 256] -> h1b cols 0..255
        dim3 grid(EMB / 128, (N_NODES + 127) / 128);
        mfma_gemm<256, 512, false><<<grid, 256, 0, stream>>>(
            xb, w1t, b1, h1b, nullptr, nullptr);
    }

    gather2_kernel<<<(N_NODES + 3) / 4, 256, 0, stream>>>(offsets, srcbuf, rinv, h1b);

    {   // layer 2: A=h1b [50000 x 512] bf16, Wt=w2t [512 x 512] -> pooled psum
        dim3 grid(HID / 128, (N_NODES + 127) / 128);
        mfma_gemm<512, 512, true><<<grid, 256, 0, stream>>>(
            h1b, w2t, b2, nullptr, psum, batch);
    }

    head_kernel<<<N_GRAPHS, 512, 0, stream>>>(psum, ncnt, Wh, bh, Wc, bc, Wout, bout, out);
}